// Round 12
// baseline (327.188 us; speedup 1.0000x reference)
//
#include <hip/hip_runtime.h>
#include <hip/hip_bf16.h>
#include <math.h>

#define DEV_INLINE __device__ __forceinline__

constexpr int B_ = 8, C_ = 512, L_ = 256;
constexpr float EPS_ = 1e-5f;

typedef __attribute__((ext_vector_type(8))) short bf16x8;
typedef __attribute__((ext_vector_type(4))) float f32x4;

DEV_INLINE int lmap1(int l) { return ((l & 15) << 4) | (l >> 4); }
DEV_INLINE float sigmoidf_(float x) { return 1.f / (1.f + __expf(-x)); }
DEV_INLINE float siluf_(float x) { return x * sigmoidf_(x); }
DEV_INLINE float ex2_(float x) { return __builtin_amdgcn_exp2f(x); }  // raw v_exp_f32

DEV_INLINE unsigned pk2(float a, float b) {
    __hip_bfloat16 x = __float2bfloat16(a), y = __float2bfloat16(b);
    unsigned short ux = *reinterpret_cast<unsigned short*>(&x);
    unsigned short uy = *reinterpret_cast<unsigned short*>(&y);
    return ((unsigned)uy << 16) | ux;
}

// ---------------- pooled = y.mean((2,3)) ----------------
__global__ __launch_bounds__(256) void k_pool(const float* __restrict__ y, float* __restrict__ pooled) {
    int bc = blockIdx.x;
    int t = threadIdx.x;
    __shared__ float red[256];
    red[t] = y[bc * 256 + t];
    __syncthreads();
    for (int s = 128; s > 0; s >>= 1) { if (t < s) red[t] += red[t + s]; __syncthreads(); }
    if (t == 0) pooled[bc] = red[0] * (1.f / 256.f);
}

// ---------------- gate = sigmoid(2 * mlp(pooled)) ----------------
__global__ __launch_bounds__(256) void k_gate(const float* __restrict__ pooled,
                                              const float* __restrict__ lin1_w, const float* __restrict__ lin1_b,
                                              const float* __restrict__ lin2_w, const float* __restrict__ lin2_b,
                                              float* __restrict__ gate) {
    int b = blockIdx.x;
    int t = threadIdx.x;
    __shared__ float p[512];
    __shared__ float h1[256];
    p[t] = pooled[b * 512 + t];
    p[t + 256] = pooled[b * 512 + t + 256];
    __syncthreads();
    float s = lin1_b[t];
    const float4* wp1 = (const float4*)(lin1_w + t * 512);
    #pragma unroll 4
    for (int c = 0; c < 128; ++c) {
        float4 pv = *(const float4*)(p + c * 4);
        float4 wv = wp1[c];
        s = fmaf(pv.x, wv.x, s); s = fmaf(pv.y, wv.y, s);
        s = fmaf(pv.z, wv.z, s); s = fmaf(pv.w, wv.w, s);
    }
    h1[t] = fmaxf(s, 0.f);
    __syncthreads();
    #pragma unroll
    for (int cc = 0; cc < 2; ++cc) {
        int c = t + cc * 256;
        float s2 = lin2_b[c];
        const float4* wp2 = (const float4*)(lin2_w + c * 256);
        #pragma unroll 4
        for (int j = 0; j < 64; ++j) {
            float4 hv = *(const float4*)(h1 + j * 4);
            float4 wv = wp2[j];
            s2 = fmaf(hv.x, wv.x, s2); s2 = fmaf(hv.y, wv.y, s2);
            s2 = fmaf(hv.z, wv.z, s2); s2 = fmaf(hv.w, wv.w, s2);
        }
        gate[b * 512 + c] = sigmoidf_(2.f * s2);
    }
}

// ---------------- LayerNorm over C at each (b,h,w); x NCHW -> xnb bf16 [pos][512] ----------------
__global__ __launch_bounds__(256) void k_ln(const float* __restrict__ x, const float* __restrict__ g,
                                            const float* __restrict__ bta, __hip_bfloat16* __restrict__ xnb) {
    int pos = blockIdx.x;
    int b = pos >> 8, l = pos & 255;
    int t = threadIdx.x;
    float v0 = x[(b * C_ + t) * L_ + l];
    float v1 = x[(b * C_ + t + 256) * L_ + l];
    __shared__ float red[256];
    red[t] = v0 + v1;
    __syncthreads();
    for (int s = 128; s > 0; s >>= 1) { if (t < s) red[t] += red[t + s]; __syncthreads(); }
    float mu = red[0] * (1.f / 512.f);
    __syncthreads();
    float d0 = v0 - mu, d1 = v1 - mu;
    red[t] = d0 * d0 + d1 * d1;
    __syncthreads();
    for (int s = 128; s > 0; s >>= 1) { if (t < s) red[t] += red[t + s]; __syncthreads(); }
    float rs = rsqrtf(red[0] * (1.f / 512.f) + EPS_);
    xnb[pos * C_ + t] = __float2bfloat16(d0 * rs * g[t] + bta[t]);
    xnb[pos * C_ + t + 256] = __float2bfloat16(d1 * rs * g[t + 256] + bta[t + 256]);
}

// ---------------- cast ALL weights to bf16 in one launch (dedicated wb region) ----------------
// elems: [inprojb 1048576][xprojb 262144][outprojb 524288][fc1b 262144][fc2b 262144][dtwb 131072][wtb 2359296]
// blocks 0..2431: the 6 GEMM weight tensors (2490368 elems). blocks 2432..3455: ffn_conv_w -> wtb [tap][co][ci]
__global__ __launch_bounds__(256) void k_wcast6(const float* __restrict__ ip, const float* __restrict__ xp,
                                                const float* __restrict__ op, const float* __restrict__ f1,
                                                const float* __restrict__ f2, const float* __restrict__ dtw,
                                                const float* __restrict__ fw, __hip_bfloat16* __restrict__ dst) {
    if (blockIdx.x < 2432) {
        size_t e = ((size_t)blockIdx.x * 256 + threadIdx.x) * 4;
        const float* src; size_t off;
        if (e < 1048576) { src = ip; off = e; }
        else if (e < 1310720) { src = xp; off = e - 1048576; }
        else if (e < 1835008) { src = op; off = e - 1310720; }
        else if (e < 2097152) { src = f1; off = e - 1835008; }
        else if (e < 2359296) { src = f2; off = e - 2097152; }
        else { src = dtw; off = e - 2359296; }
        float4 v = *(const float4*)(src + off);
        uint2 o; o.x = pk2(v.x, v.y); o.y = pk2(v.z, v.w);
        *(uint2*)(dst + e) = o;
    } else {
        int gid = (blockIdx.x - 2432) * 256 + threadIdx.x;  // co*512+ci
        __hip_bfloat16* wt = dst + 2490368;
        const float* src = fw + (size_t)gid * 9;
        #pragma unroll
        for (int tap = 0; tap < 9; ++tap) wt[(size_t)tap * 262144 + gid] = __float2bfloat16(src[tap]);
    }
}

// ---------------- unified bf16-MFMA GEMM, 64x64 tile, BK=32, fused epilogues ----------------
enum { M_INPROJ = 0, M_XDBL = 1, M_OUTPROJ = 2, M_FC1 = 3, M_FC2 = 4, M_DELTA = 5 };

template <int MODE>
__global__ __launch_bounds__(256) void gemm_mfma(const void* __restrict__ Aptr, const __hip_bfloat16* __restrict__ Wb,
                                                 float* __restrict__ O, float* __restrict__ O2,
                                                 const float* __restrict__ AUX, __hip_bfloat16* __restrict__ Ob) {
    constexpr int KK = (MODE == M_XDBL || MODE == M_OUTPROJ) ? 1024 : (MODE == M_DELTA) ? 32 : 512;
    constexpr bool A_COPY = (MODE == M_INPROJ || MODE == M_OUTPROJ || MODE == M_FC1 || MODE == M_FC2);
    __shared__ short Asm[64 * 32];
    __shared__ short Bsm[64 * 32];
    const int t = threadIdx.x;
    const int lane = t & 63, wv = t >> 6;
    int m0, n0 = 0, kdir = 0, bq = 0;
    if constexpr (MODE == M_XDBL) { m0 = blockIdx.x * 64; kdir = blockIdx.y; }
    else if constexpr (MODE == M_FC2) { bq = blockIdx.x >> 3; m0 = (blockIdx.x & 7) * 64; n0 = blockIdx.y * 64; }
    else { m0 = blockIdx.x * 64; n0 = blockIdx.y * 64; }
    const int kdel = (m0 >> 8) & 3;  // bk's k for M_DELTA

    const int r_ = t >> 2, kq = t & 3;
    const int skey = (r_ >> 1) & 3;
    uint4* adst = (uint4*)(Asm + r_ * 32) + (kq ^ skey);
    uint4* bdst = (uint4*)(Bsm + r_ * 32) + (kq ^ skey);

    // ---- A-side source row ----
    const float* arowf = nullptr;
    const __hip_bfloat16* arowb = nullptr;
    if constexpr (MODE == M_INPROJ) arowb = (const __hip_bfloat16*)Aptr + (size_t)(m0 + r_) * 512 + kq * 8;
    else if constexpr (MODE == M_XDBL) {
        int m = m0 + r_; int b = m >> 8, l = m & 255;
        int lm = (kdir < 2) ? l : 255 - l;
        arowf = (const float*)Aptr + (size_t)((b * 2 + (kdir & 1)) * 256 + lm) * 1024 + kq * 8;
    } else if constexpr (MODE == M_OUTPROJ) arowb = (const __hip_bfloat16*)Aptr + (size_t)(m0 + r_) * 1024 + kq * 8;
    else if constexpr (MODE == M_FC1) arowb = (const __hip_bfloat16*)Aptr + (size_t)(m0 + r_) * 512 + kq * 8;
    else if constexpr (MODE == M_DELTA) arowf = (const float*)Aptr + (size_t)(m0 + r_) * 64 + kq * 8;
    else arowb = Wb + (size_t)(m0 + r_) * 512 + kq * 8;  // FC2: A = fc2 weights bf16

    // ---- B-side source row (always bf16 now) ----
    const __hip_bfloat16* browb = nullptr;
    if constexpr (MODE == M_INPROJ) browb = Wb + (size_t)(n0 + r_) * 512 + kq * 8;
    else if constexpr (MODE == M_XDBL) browb = Wb + (size_t)(kdir * 64 + r_) * 1024 + kq * 8;
    else if constexpr (MODE == M_OUTPROJ) browb = Wb + (size_t)(n0 + r_) * 1024 + kq * 8;
    else if constexpr (MODE == M_FC1) browb = Wb + (size_t)(n0 + r_) * 512 + kq * 8;
    else if constexpr (MODE == M_DELTA) browb = Wb + ((size_t)(kdel * 1024 + n0 + r_)) * 32 + kq * 8;
    else browb = (const __hip_bfloat16*)Aptr + (size_t)(bq * 256 + n0 + r_) * 512 + kq * 8;  // FC2: B = t2 bf16

    f32x4 acc[4];
    #pragma unroll
    for (int nf = 0; nf < 4; ++nf) acc[nf] = (f32x4){0.f, 0.f, 0.f, 0.f};

    for (int k0 = 0; k0 < KK; k0 += 32) {
        __syncthreads();
        if constexpr (A_COPY) {
            *adst = *(const uint4*)(arowb + k0);
        } else {
            float4 u0 = *(const float4*)(arowf + k0);
            float4 u1 = *(const float4*)(arowf + k0 + 4);
            uint4 pk; pk.x = pk2(u0.x, u0.y); pk.y = pk2(u0.z, u0.w); pk.z = pk2(u1.x, u1.y); pk.w = pk2(u1.z, u1.w);
            *adst = pk;
        }
        *bdst = *(const uint4*)(browb + k0);
        __syncthreads();
        int mrow = wv * 16 + (lane & 15);
        int ks = lane >> 4;
        bf16x8 af = *(const bf16x8*)(Asm + mrow * 32 + ((ks ^ ((mrow >> 1) & 3)) * 8));
        #pragma unroll
        for (int nf = 0; nf < 4; ++nf) {
            int nrow = nf * 16 + (lane & 15);
            bf16x8 bfv = *(const bf16x8*)(Bsm + nrow * 32 + ((ks ^ ((nrow >> 1) & 3)) * 8));
            acc[nf] = __builtin_amdgcn_mfma_f32_16x16x32_bf16(af, bfv, acc[nf], 0, 0, 0);
        }
    }

    const int mlb = (lane >> 4) * 4, nl = lane & 15;
    #pragma unroll
    for (int nf = 0; nf < 4; ++nf) {
        #pragma unroll
        for (int j = 0; j < 4; ++j) {
            float v = acc[nf][j];
            int m_loc = wv * 16 + mlb + j;
            int n_loc = nf * 16 + nl;
            if constexpr (MODE == M_INPROJ) {
                int m = m0 + m_loc, n = n0 + n_loc;
                if (n0 < 1024) O[(size_t)m * 1024 + n] = v;           // xa pos-major f32
                else O2[(size_t)m * 1024 + (n - 1024)] = v;           // z pos-major f32
            } else if constexpr (MODE == M_XDBL) {
                int m = m0 + m_loc; int b = m >> 8, l = m & 255;
                O[((size_t)(b * 4 + kdir) * 256 + l) * 64 + n_loc] = v;
            } else if constexpr (MODE == M_OUTPROJ) {
                int m = m0 + m_loc, n = n0 + n_loc; int b = m >> 8, l = m & 255;
                float f = AUX[((size_t)b * 512 + n) * 256 + l] + v;   // + residual x (NCHW)
                Ob[(size_t)m * 512 + n] = __float2bfloat16(f);        // vssb
            } else if constexpr (MODE == M_FC1) {
                int m = m0 + m_loc, n = n0 + n_loc;
                float gl = 0.5f * v * (1.f + erff(v * 0.70710678118f));
                Ob[(size_t)m * 512 + n] = __float2bfloat16(gl);       // t2 bf16
            } else if constexpr (MODE == M_DELTA) {
                int m = m0 + m_loc, n = n0 + n_loc;   // m = bk*256+l, n = d
                int bkk = m >> 8, l = m & 255;
                float v2 = v + AUX[kdel * 1024 + n];  // + dt_b
                float dlt = (v2 > 20.f) ? v2 : __logf(1.f + __expf(v2));
                O[((((size_t)bkk * 32) + (n >> 5)) * 256 + l) * 32 + (n & 31)] = dlt;  // tiled dys
            } else {  // FC2: m=c, n=l
                int c = m0 + m_loc, n = n0 + n_loc;
                O[((size_t)(bq * 512 + c)) * 256 + n] = v * AUX[bq * 512 + c];
            }
        }
    }
}

// ---------------- depthwise 3x3 + bias + SiLU; xa pos-major -> xs_t[b][j][l][1024] ----------------
__global__ __launch_bounds__(256) void k_dwconv2(const float* __restrict__ xa, const float* __restrict__ cw,
                                                 const float* __restrict__ cb, float* __restrict__ xs_t) {
    int pos = blockIdx.x;
    int b = pos >> 8, l = pos & 255;
    int h = l >> 4, w = l & 15;
    int t = threadIdx.x;
    int d = t * 4;
    float wv[36];
    {
        const float4* cp = (const float4*)(cw + (size_t)d * 9);
        #pragma unroll
        for (int j = 0; j < 9; ++j) { float4 v = cp[j]; wv[j*4] = v.x; wv[j*4+1] = v.y; wv[j*4+2] = v.z; wv[j*4+3] = v.w; }
    }
    float4 bias = *(const float4*)(cb + d);
    float a0 = bias.x, a1 = bias.y, a2 = bias.z, a3 = bias.w;
    #pragma unroll
    for (int ky = -1; ky <= 1; ++ky) {
        int hh = h + ky;
        if ((unsigned)hh >= 16u) continue;
        #pragma unroll
        for (int kx = -1; kx <= 1; ++kx) {
            int ww = w + kx;
            if ((unsigned)ww >= 16u) continue;
            float4 v = *(const float4*)(xa + (size_t)(b * 256 + hh * 16 + ww) * 1024 + d);
            int tap = (ky + 1) * 3 + (kx + 1);
            a0 = fmaf(v.x, wv[0 * 9 + tap], a0);
            a1 = fmaf(v.y, wv[1 * 9 + tap], a1);
            a2 = fmaf(v.z, wv[2 * 9 + tap], a2);
            a3 = fmaf(v.w, wv[3 * 9 + tap], a3);
        }
    }
    float4 o; o.x = siluf_(a0); o.y = siluf_(a1); o.z = siluf_(a2); o.w = siluf_(a3);
    *(float4*)(xs_t + ((size_t)(b * 2 + 0) * 256 + l) * 1024 + d) = o;
    *(float4*)(xs_t + ((size_t)(b * 2 + 1) * 256 + lmap1(l)) * 1024 + d) = o;
}

// ---------------- selective scan v8: v7 + dl/u kept in registers across passes ----------------
// dys layout: [bk][db(32)][l(256)][dd(32)]
__global__ __launch_bounds__(512) void k_scan8(const float* __restrict__ xs_t, const float* __restrict__ x_dbl,
                                               const float* __restrict__ A_logs, const float* __restrict__ Ds,
                                               float* __restrict__ dys) {
    const int bk = blockIdx.x >> 5;
    const int db = blockIdx.x & 31;
    const int b = bk >> 2, k = bk & 3;
    const int t = threadIdx.x;
    const int c = t >> 5, dd = t & 31;
    const int d = db * 32 + dd;
    const bool rev = (k >= 2);

    __shared__ float Ssh[16][33];
    __shared__ float locH[16][32][17];

    float An2[16];
    {
        const float* alp = A_logs + (size_t)(k * 1024 + d) * 16;
        #pragma unroll
        for (int i = 0; i < 16; ++i) An2[i] = -__expf(alp[i]) * 1.44269504088896f;
    }
    const float Dv = Ds[k * 1024 + d];

    const int lbeg = c * 16;
    float* yp = dys + (((size_t)bk * 32 + db) * 256 + lbeg) * 32 + dd;
    const float* up = xs_t + ((size_t)(b * 2 + (k & 1)) * 256 + (rev ? 255 - lbeg : lbeg)) * 1024 + d;
    const ptrdiff_t ustr = rev ? -1024 : 1024;
    const float* xc = x_dbl + (size_t)bk * 256 * 64 + lbeg * 64;

    float h[16];
    #pragma unroll
    for (int i = 0; i < 16; ++i) h[i] = 0.f;
    float S = 0.f;
    float dls[16], us_[16];

    // ---- pass 1: local scan from h=0; keep dl,u in regs ----
    #pragma unroll
    for (int li = 0; li < 16; ++li) {
        float dl = yp[li * 32];
        float u = up[(ptrdiff_t)li * ustr];
        dls[li] = dl; us_[li] = u;
        S += dl;
        float du = dl * u;
        #pragma unroll
        for (int q = 0; q < 4; ++q) {
            float4 Bq = *(const float4*)(xc + li * 64 + 32 + q * 4);
            h[q*4+0] = fmaf(ex2_(dl * An2[q*4+0]), h[q*4+0], du * Bq.x);
            h[q*4+1] = fmaf(ex2_(dl * An2[q*4+1]), h[q*4+1], du * Bq.y);
            h[q*4+2] = fmaf(ex2_(dl * An2[q*4+2]), h[q*4+2], du * Bq.z);
            h[q*4+3] = fmaf(ex2_(dl * An2[q*4+3]), h[q*4+3], du * Bq.w);
        }
    }
    Ssh[c][dd] = S;
    #pragma unroll
    for (int i = 0; i < 16; ++i) locH[c][dd][i] = h[i];
    __syncthreads();

    // ---- middle: compose preceding chunks in order ----
    #pragma unroll
    for (int i = 0; i < 16; ++i) h[i] = 0.f;
    for (int j = 0; j < c; ++j) {
        float Sj = Ssh[j][dd];
        #pragma unroll
        for (int i = 0; i < 16; ++i) h[i] = fmaf(ex2_(Sj * An2[i]), h[i], locH[j][dd][i]);
    }

    // ---- pass 2: re-scan from correct h_start, emit ys ----
    #pragma unroll
    for (int li = 0; li < 16; ++li) {
        float dl = dls[li];
        float u = us_[li];
        float du = dl * u;
        float yv = 0.f;
        #pragma unroll
        for (int q = 0; q < 4; ++q) {
            float4 Bq = *(const float4*)(xc + li * 64 + 32 + q * 4);
            float4 Cq = *(const float4*)(xc + li * 64 + 48 + q * 4);
            h[q*4+0] = fmaf(ex2_(dl * An2[q*4+0]), h[q*4+0], du * Bq.x); yv = fmaf(h[q*4+0], Cq.x, yv);
            h[q*4+1] = fmaf(ex2_(dl * An2[q*4+1]), h[q*4+1], du * Bq.y); yv = fmaf(h[q*4+1], Cq.y, yv);
            h[q*4+2] = fmaf(ex2_(dl * An2[q*4+2]), h[q*4+2], du * Bq.z); yv = fmaf(h[q*4+2], Cq.z, yv);
            h[q*4+3] = fmaf(ex2_(dl * An2[q*4+3]), h[q*4+3], du * Bq.w); yv = fmaf(h[q*4+3], Cq.w, yv);
        }
        yp[li * 32] = yv + u * Dv;
    }
}

// ---------------- combine 4 dirs + out_norm LN + silu(z) -> yc bf16 pos-major ----------------
__global__ __launch_bounds__(256) void k_combine(const float* __restrict__ dys, const float* __restrict__ z,
                                                 const float* __restrict__ g, const float* __restrict__ bb,
                                                 __hip_bfloat16* __restrict__ ycb) {
    int pos = blockIdx.x;
    int b = pos >> 8, l = pos & 255;
    int t = threadIdx.x;
    int lw = lmap1(l);
    int db0 = t >> 5, dd = t & 31;
    float v[4];
    float psum = 0.f;
    #pragma unroll
    for (int q = 0; q < 4; ++q) {
        int dbq = db0 + q * 8;
        float s0 = dys[((((size_t)(b * 4 + 0) * 32) + dbq) * 256 + l) * 32 + dd];
        float s1 = dys[((((size_t)(b * 4 + 1) * 32) + dbq) * 256 + lw) * 32 + dd];
        float s2 = dys[((((size_t)(b * 4 + 2) * 32) + dbq) * 256 + (255 - l)) * 32 + dd];
        float s3 = dys[((((size_t)(b * 4 + 3) * 32) + dbq) * 256 + (255 - lw)) * 32 + dd];
        v[q] = s0 + s1 + s2 + s3;
        psum += v[q];
    }
    __shared__ float red[256];
    red[t] = psum;
    __syncthreads();
    for (int s = 128; s > 0; s >>= 1) { if (t < s) red[t] += red[t + s]; __syncthreads(); }
    float mu = red[0] * (1.f / 1024.f);
    __syncthreads();
    float p2 = 0.f;
    #pragma unroll
    for (int q = 0; q < 4; ++q) { float ddv = v[q] - mu; p2 += ddv * ddv; }
    red[t] = p2;
    __syncthreads();
    for (int s = 128; s > 0; s >>= 1) { if (t < s) red[t] += red[t + s]; __syncthreads(); }
    float rs = rsqrtf(red[0] * (1.f / 1024.f) + EPS_);
    #pragma unroll
    for (int q = 0; q < 4; ++q) {
        int d = (db0 + q * 8) * 32 + dd;
        float zn = z[(size_t)pos * 1024 + d];
        float o = ((v[q] - mu) * rs * g[d] + bb[d]) * siluf_(zn);
        ycb[(size_t)pos * 1024 + d] = __float2bfloat16(o);
    }
}

// ---------------- implicit-GEMM 3x3 conv via bf16 MFMA, 8-way K-split over ci ----------------
__global__ __launch_bounds__(256) void k_conv2m(const __hip_bfloat16* __restrict__ vssb,
                                                const __hip_bfloat16* __restrict__ wt,
                                                float* __restrict__ convp) {
    __shared__ short Asm[18 * 18 * 32];
    __shared__ short Bsm[9 * 64 * 32];
    const int b = blockIdx.x, co0 = blockIdx.y * 64, split = blockIdx.z;  // split 0..7
    const int t = threadIdx.x;
    const int lane = t & 63, wid = t >> 6;
    const int wcol = lane & 15, slot = lane >> 4;

    f32x4 acc[4][4];
    #pragma unroll
    for (int r = 0; r < 4; ++r)
        #pragma unroll
        for (int g = 0; g < 4; ++g) acc[r][g] = (f32x4){0.f, 0.f, 0.f, 0.f};

    for (int ch = 0; ch < 2; ++ch) {
        const int ci0 = split * 64 + ch * 32;
        __syncthreads();
        for (int i = t; i < 324; i += 256) {
            int row = i / 18, col = i - row * 18;
            uint4 v0 = {0,0,0,0}, v1 = {0,0,0,0}, v2 = {0,0,0,0}, v3 = {0,0,0,0};
            if (row >= 1 && row <= 16 && col >= 1 && col <= 16) {
                const uint4* src = (const uint4*)(vssb + ((size_t)(b * 256 + (row - 1) * 16 + (col - 1)) * 512 + ci0));
                v0 = src[0]; v1 = src[1]; v2 = src[2]; v3 = src[3];
            }
            uint4* dst = (uint4*)(Asm + i * 32);
            int key = (col >> 1) & 3;
            dst[0 ^ key] = v0; dst[1 ^ key] = v1; dst[2 ^ key] = v2; dst[3 ^ key] = v3;
        }
        for (int i = t; i < 576; i += 256) {
            int tap = i >> 6, col = i & 63;
            const uint4* src = (const uint4*)(wt + ((size_t)(tap * 512 + co0 + col) * 512 + ci0));
            uint4* dst = (uint4*)(Bsm + i * 32);
            int key = (col >> 1) & 3;
            dst[0 ^ key] = src[0]; dst[1 ^ key] = src[1]; dst[2 ^ key] = src[2]; dst[3 ^ key] = src[3];
        }
        __syncthreads();
        #pragma unroll
        for (int tap = 0; tap < 9; ++tap) {
            const int ky = tap / 3, kx = tap - ky * 3;
            bf16x8 af[4], bfr[4];
            #pragma unroll
            for (int r = 0; r < 4; ++r) {
                int crow = wid * 4 + r + ky;
                int ccol = wcol + kx;
                int s2 = slot ^ ((ccol >> 1) & 3);
                af[r] = *(const bf16x8*)(Asm + ((crow * 18 + ccol) * 32 + s2 * 8));
            }
            #pragma unroll
            for (int g = 0; g < 4; ++g) {
                int col = g * 16 + wcol;
                int s2 = slot ^ ((col >> 1) & 3);
                bfr[g] = *(const bf16x8*)(Bsm + ((tap * 64 + col) * 32 + s2 * 8));
            }
            #pragma unroll
            for (int r = 0; r < 4; ++r)
                #pragma unroll
                for (int g = 0; g < 4; ++g)
                    acc[r][g] = __builtin_amdgcn_mfma_f32_16x16x32_bf16(af[r], bfr[g], acc[r][g], 0, 0, 0);
        }
    }
    float* base = convp + (size_t)split * 1048576 + (size_t)b * 512 * 256;
    #pragma unroll
    for (int r = 0; r < 4; ++r) {
        int h = wid * 4 + r;
        #pragma unroll
        for (int g = 0; g < 4; ++g) {
            int co = co0 + g * 16 + wcol;
            *(f32x4*)(base + (size_t)co * 256 + h * 16 + slot * 4) = acc[r][g];
        }
    }
}

// ---------------- reduce 8 K-splits + BN + relu6 -> t1 bf16 POS-MAJOR [b*256+pos][512] ----------------
__global__ __launch_bounds__(256) void k_convred2(const float* __restrict__ convp,
                                                  const float* __restrict__ bn_g, const float* __restrict__ bn_b,
                                                  const float* __restrict__ bn_mean, const float* __restrict__ bn_var,
                                                  __hip_bfloat16* __restrict__ t1b) {
    int b = blockIdx.x >> 7, cb = (blockIdx.x >> 3) & 15, pb = blockIdx.x & 7;
    int co0 = cb * 32, pos0 = pb * 32;
    int t = threadIdx.x;
    int ti = t >> 5, tj = t & 31;
    __shared__ float tile[32][33];
    #pragma unroll
    for (int r = 0; r < 4; ++r) {
        int co = co0 + ti + r * 8;
        size_t idx = ((size_t)b * 512 + co) * 256 + pos0 + tj;
        float s = 0.f;
        #pragma unroll
        for (int sp = 0; sp < 8; ++sp) s += convp[idx + (size_t)sp * 1048576];
        float o = (s - bn_mean[co]) * rsqrtf(bn_var[co] + EPS_) * bn_g[co] + bn_b[co];
        tile[ti + r * 8][tj] = fminf(fmaxf(o, 0.f), 6.f);
    }
    __syncthreads();
    #pragma unroll
    for (int r = 0; r < 4; ++r) {
        int pos = pos0 + ti + r * 8;
        t1b[((size_t)b * 256 + pos) * 512 + co0 + tj] = __float2bfloat16(tile[tj][ti + r * 8]);
    }
}

extern "C" void kernel_launch(void* const* d_in, const int* in_sizes, int n_in,
                              void* d_out, int out_size, void* d_ws, size_t ws_size,
                              hipStream_t stream) {
    const float* x = (const float*)d_in[0];
    const float* y = (const float*)d_in[1];
    const float* ln1_g = (const float*)d_in[2];
    const float* ln1_b = (const float*)d_in[3];
    const float* in_proj_w = (const float*)d_in[4];
    const float* conv_w = (const float*)d_in[5];
    const float* conv_b = (const float*)d_in[6];
    const float* x_proj_w = (const float*)d_in[7];
    const float* dt_w = (const float*)d_in[8];
    const float* dt_b = (const float*)d_in[9];
    const float* A_logs = (const float*)d_in[10];
    const float* Ds = (const float*)d_in[11];
    const float* out_norm_g = (const float*)d_in[12];
    const float* out_norm_b = (const float*)d_in[13];
    const float* out_proj_w = (const float*)d_in[14];
    const float* ffn_conv_w = (const float*)d_in[15];
    const float* bn_g = (const float*)d_in[16];
    const float* bn_b = (const float*)d_in[17];
    const float* bn_mean = (const float*)d_in[18];
    const float* bn_var = (const float*)d_in[19];
    const float* fc1_w = (const float*)d_in[20];
    const float* fc2_w = (const float*)d_in[21];
    const float* lin1_w = (const float*)d_in[22];
    const float* lin1_b = (const float*)d_in[23];
    const float* lin2_w = (const float*)d_in[24];
    const float* lin2_b = (const float*)d_in[25];
    float* out = (float*)d_out;

    char* ws = (char*)d_ws;
    size_t off = 0;
    auto alloc = [&](size_t nf) { float* p = (float*)(ws + off); off += nf * sizeof(float); return p; };
    float* xn    = alloc(2048u * 512);        // 4MB; xnb bf16 (2MB), then vssb bf16 (2MB)
    float* xa    = alloc(2048u * 1024);       // 8MB f32 pos-major; then ycb bf16 (4MB)
    float* z     = alloc(2048u * 1024);       // 8MB z pos-major f32 (no other use now)
    float* xs_t  = alloc(2u * 2048 * 1024);   // 16MB f32; then t1b bf16 (2MB) + t2b bf16 (2MB)
    float* x_dbl = alloc(8u * 4 * 256 * 64);  // 2MB
    float* ys_t  = alloc(4u * 2048 * 1024);   // 32MB; tiled delta/ys; then convp (32MB)
    float* wb    = alloc(2424832);            // 9.25MB bf16 weights (7 tensors incl. ffn conv)
    float* pooled = alloc(4096);
    float* gate   = alloc(4096);

    __hip_bfloat16* xnb = (__hip_bfloat16*)xn;
    __hip_bfloat16* vssb = (__hip_bfloat16*)xn;         // after xnb dead
    __hip_bfloat16* ycb = (__hip_bfloat16*)xa;          // after xa f32 dead
    __hip_bfloat16* t1b = (__hip_bfloat16*)xs_t;        // after scan done
    __hip_bfloat16* t2b = (__hip_bfloat16*)(xs_t + 2048u * 512);
    float* convp = ys_t;
    __hip_bfloat16* inprojb = (__hip_bfloat16*)wb;
    __hip_bfloat16* xprojb  = inprojb + 1048576;
    __hip_bfloat16* outprojb = xprojb + 262144;
    __hip_bfloat16* fc1b = outprojb + 524288;
    __hip_bfloat16* fc2b = fc1b + 262144;
    __hip_bfloat16* dtwb = fc2b + 262144;
    __hip_bfloat16* w_t  = dtwb + 131072;               // ffn conv weights, dedicated

    k_wcast6<<<3456, 256, 0, stream>>>(in_proj_w, x_proj_w, out_proj_w, fc1_w, fc2_w, dt_w, ffn_conv_w, inprojb);
    k_pool<<<4096, 256, 0, stream>>>(y, pooled);
    k_gate<<<8, 256, 0, stream>>>(pooled, lin1_w, lin1_b, lin2_w, lin2_b, gate);
    k_ln<<<2048, 256, 0, stream>>>(x, ln1_g, ln1_b, xnb);
    gemm_mfma<M_INPROJ><<<dim3(32, 32), 256, 0, stream>>>(xnb, inprojb, xa, z, nullptr, nullptr);
    k_dwconv2<<<2048, 256, 0, stream>>>(xa, conv_w, conv_b, xs_t);
    gemm_mfma<M_XDBL><<<dim3(32, 4), 256, 0, stream>>>(xs_t, xprojb, x_dbl, nullptr, nullptr, nullptr);
    gemm_mfma<M_DELTA><<<dim3(128, 16), 256, 0, stream>>>(x_dbl, dtwb, ys_t, nullptr, dt_b, nullptr);
    k_scan8<<<1024, 512, 0, stream>>>(xs_t, x_dbl, A_logs, Ds, ys_t);
    k_combine<<<2048, 256, 0, stream>>>(ys_t, z, out_norm_g, out_norm_b, ycb);
    gemm_mfma<M_OUTPROJ><<<dim3(32, 8), 256, 0, stream>>>(ycb, outprojb, nullptr, nullptr, x, vssb);
    k_conv2m<<<dim3(8, 8, 8), 256, 0, stream>>>(vssb, w_t, convp);
    k_convred2<<<1024, 256, 0, stream>>>(convp, bn_g, bn_b, bn_mean, bn_var, t1b);
    gemm_mfma<M_FC1><<<dim3(32, 8), 256, 0, stream>>>(t1b, fc1b, nullptr, nullptr, nullptr, t2b);
    gemm_mfma<M_FC2><<<dim3(64, 4), 256, 0, stream>>>(t2b, fc2b, out, nullptr, gate, nullptr);
}

// Round 13
// 247.188 us; speedup vs baseline: 1.3236x; 1.3236x over previous
//
#include <hip/hip_runtime.h>
#include <hip/hip_bf16.h>
#include <math.h>

#define DEV_INLINE __device__ __forceinline__

constexpr int B_ = 8, C_ = 512, L_ = 256;
constexpr float EPS_ = 1e-5f;

typedef __attribute__((ext_vector_type(8))) short bf16x8;
typedef __attribute__((ext_vector_type(4))) float f32x4;

DEV_INLINE int lmap1(int l) { return ((l & 15) << 4) | (l >> 4); }
DEV_INLINE float sigmoidf_(float x) { return 1.f / (1.f + __expf(-x)); }
DEV_INLINE float siluf_(float x) { return x * sigmoidf_(x); }
DEV_INLINE float ex2_(float x) { return __builtin_amdgcn_exp2f(x); }  // raw v_exp_f32

DEV_INLINE unsigned pk2(float a, float b) {
    __hip_bfloat16 x = __float2bfloat16(a), y = __float2bfloat16(b);
    unsigned short ux = *reinterpret_cast<unsigned short*>(&x);
    unsigned short uy = *reinterpret_cast<unsigned short*>(&y);
    return ((unsigned)uy << 16) | ux;
}

// ---------------- pooled = y.mean((2,3)) ----------------
__global__ __launch_bounds__(256) void k_pool(const float* __restrict__ y, float* __restrict__ pooled) {
    int bc = blockIdx.x;
    int t = threadIdx.x;
    __shared__ float red[256];
    red[t] = y[bc * 256 + t];
    __syncthreads();
    for (int s = 128; s > 0; s >>= 1) { if (t < s) red[t] += red[t + s]; __syncthreads(); }
    if (t == 0) pooled[bc] = red[0] * (1.f / 256.f);
}

// ---------------- gate = sigmoid(2 * mlp(pooled)) ----------------
__global__ __launch_bounds__(256) void k_gate(const float* __restrict__ pooled,
                                              const float* __restrict__ lin1_w, const float* __restrict__ lin1_b,
                                              const float* __restrict__ lin2_w, const float* __restrict__ lin2_b,
                                              float* __restrict__ gate) {
    int b = blockIdx.x;
    int t = threadIdx.x;
    __shared__ float p[512];
    __shared__ float h1[256];
    p[t] = pooled[b * 512 + t];
    p[t + 256] = pooled[b * 512 + t + 256];
    __syncthreads();
    float s = lin1_b[t];
    const float4* wp1 = (const float4*)(lin1_w + t * 512);
    #pragma unroll 4
    for (int c = 0; c < 128; ++c) {
        float4 pv = *(const float4*)(p + c * 4);
        float4 wv = wp1[c];
        s = fmaf(pv.x, wv.x, s); s = fmaf(pv.y, wv.y, s);
        s = fmaf(pv.z, wv.z, s); s = fmaf(pv.w, wv.w, s);
    }
    h1[t] = fmaxf(s, 0.f);
    __syncthreads();
    #pragma unroll
    for (int cc = 0; cc < 2; ++cc) {
        int c = t + cc * 256;
        float s2 = lin2_b[c];
        const float4* wp2 = (const float4*)(lin2_w + c * 256);
        #pragma unroll 4
        for (int j = 0; j < 64; ++j) {
            float4 hv = *(const float4*)(h1 + j * 4);
            float4 wv = wp2[j];
            s2 = fmaf(hv.x, wv.x, s2); s2 = fmaf(hv.y, wv.y, s2);
            s2 = fmaf(hv.z, wv.z, s2); s2 = fmaf(hv.w, wv.w, s2);
        }
        gate[b * 512 + c] = sigmoidf_(2.f * s2);
    }
}

// ---------------- LayerNorm over C at each (b,h,w); x NCHW -> xnb bf16 [pos][512] ----------------
__global__ __launch_bounds__(256) void k_ln(const float* __restrict__ x, const float* __restrict__ g,
                                            const float* __restrict__ bta, __hip_bfloat16* __restrict__ xnb) {
    int pos = blockIdx.x;
    int b = pos >> 8, l = pos & 255;
    int t = threadIdx.x;
    float v0 = x[(b * C_ + t) * L_ + l];
    float v1 = x[(b * C_ + t + 256) * L_ + l];
    __shared__ float red[256];
    red[t] = v0 + v1;
    __syncthreads();
    for (int s = 128; s > 0; s >>= 1) { if (t < s) red[t] += red[t + s]; __syncthreads(); }
    float mu = red[0] * (1.f / 512.f);
    __syncthreads();
    float d0 = v0 - mu, d1 = v1 - mu;
    red[t] = d0 * d0 + d1 * d1;
    __syncthreads();
    for (int s = 128; s > 0; s >>= 1) { if (t < s) red[t] += red[t + s]; __syncthreads(); }
    float rs = rsqrtf(red[0] * (1.f / 512.f) + EPS_);
    xnb[pos * C_ + t] = __float2bfloat16(d0 * rs * g[t] + bta[t]);
    xnb[pos * C_ + t + 256] = __float2bfloat16(d1 * rs * g[t + 256] + bta[t + 256]);
}

// ---------------- cast ALL weights to bf16 in one launch (dedicated wb region) ----------------
// elems: [inprojb 1048576][xprojb 262144][outprojb 524288][fc1b 262144][fc2b 262144][dtwb 131072][wtb 2359296]
__global__ __launch_bounds__(256) void k_wcast6(const float* __restrict__ ip, const float* __restrict__ xp,
                                                const float* __restrict__ op, const float* __restrict__ f1,
                                                const float* __restrict__ f2, const float* __restrict__ dtw,
                                                const float* __restrict__ fw, __hip_bfloat16* __restrict__ dst) {
    if (blockIdx.x < 2432) {
        size_t e = ((size_t)blockIdx.x * 256 + threadIdx.x) * 4;
        const float* src; size_t off;
        if (e < 1048576) { src = ip; off = e; }
        else if (e < 1310720) { src = xp; off = e - 1048576; }
        else if (e < 1835008) { src = op; off = e - 1310720; }
        else if (e < 2097152) { src = f1; off = e - 1835008; }
        else if (e < 2359296) { src = f2; off = e - 2097152; }
        else { src = dtw; off = e - 2359296; }
        float4 v = *(const float4*)(src + off);
        uint2 o; o.x = pk2(v.x, v.y); o.y = pk2(v.z, v.w);
        *(uint2*)(dst + e) = o;
    } else {
        int gid = (blockIdx.x - 2432) * 256 + threadIdx.x;  // co*512+ci
        __hip_bfloat16* wt = dst + 2490368;
        const float* src = fw + (size_t)gid * 9;
        #pragma unroll
        for (int tap = 0; tap < 9; ++tap) wt[(size_t)tap * 262144 + gid] = __float2bfloat16(src[tap]);
    }
}

// ---------------- unified bf16-MFMA GEMM, 64x64 tile, BK=32, fused epilogues ----------------
enum { M_INPROJ = 0, M_XDBL = 1, M_OUTPROJ = 2, M_FC1 = 3, M_FC2 = 4, M_DELTA = 5 };

template <int MODE>
__global__ __launch_bounds__(256) void gemm_mfma(const void* __restrict__ Aptr, const __hip_bfloat16* __restrict__ Wb,
                                                 float* __restrict__ O, float* __restrict__ O2,
                                                 const float* __restrict__ AUX, __hip_bfloat16* __restrict__ Ob) {
    constexpr int KK = (MODE == M_XDBL || MODE == M_OUTPROJ) ? 1024 : (MODE == M_DELTA) ? 32 : 512;
    constexpr bool A_COPY = (MODE == M_INPROJ || MODE == M_OUTPROJ || MODE == M_FC1 || MODE == M_FC2);
    __shared__ short Asm[64 * 32];
    __shared__ short Bsm[64 * 32];
    const int t = threadIdx.x;
    const int lane = t & 63, wv = t >> 6;
    int m0, n0 = 0, kdir = 0, bq = 0;
    if constexpr (MODE == M_XDBL) { m0 = blockIdx.x * 64; kdir = blockIdx.y; }
    else if constexpr (MODE == M_FC2) { bq = blockIdx.x >> 3; m0 = (blockIdx.x & 7) * 64; n0 = blockIdx.y * 64; }
    else { m0 = blockIdx.x * 64; n0 = blockIdx.y * 64; }
    const int kdel = (m0 >> 8) & 3;  // bk's k for M_DELTA

    const int r_ = t >> 2, kq = t & 3;
    const int skey = (r_ >> 1) & 3;
    uint4* adst = (uint4*)(Asm + r_ * 32) + (kq ^ skey);
    uint4* bdst = (uint4*)(Bsm + r_ * 32) + (kq ^ skey);

    // ---- A-side source row ----
    const float* arowf = nullptr;
    const __hip_bfloat16* arowb = nullptr;
    if constexpr (MODE == M_INPROJ) arowb = (const __hip_bfloat16*)Aptr + (size_t)(m0 + r_) * 512 + kq * 8;
    else if constexpr (MODE == M_XDBL) {
        int m = m0 + r_; int b = m >> 8, l = m & 255;
        int lm = (kdir < 2) ? l : 255 - l;
        arowf = (const float*)Aptr + (size_t)((b * 2 + (kdir & 1)) * 256 + lm) * 1024 + kq * 8;
    } else if constexpr (MODE == M_OUTPROJ) arowb = (const __hip_bfloat16*)Aptr + (size_t)(m0 + r_) * 1024 + kq * 8;
    else if constexpr (MODE == M_FC1) arowb = (const __hip_bfloat16*)Aptr + (size_t)(m0 + r_) * 512 + kq * 8;
    else if constexpr (MODE == M_DELTA) arowf = (const float*)Aptr + (size_t)(m0 + r_) * 64 + kq * 8;
    else arowb = Wb + (size_t)(m0 + r_) * 512 + kq * 8;  // FC2: A = fc2 weights bf16

    // ---- B-side source row (always bf16 now) ----
    const __hip_bfloat16* browb = nullptr;
    if constexpr (MODE == M_INPROJ) browb = Wb + (size_t)(n0 + r_) * 512 + kq * 8;
    else if constexpr (MODE == M_XDBL) browb = Wb + (size_t)(kdir * 64 + r_) * 1024 + kq * 8;
    else if constexpr (MODE == M_OUTPROJ) browb = Wb + (size_t)(n0 + r_) * 1024 + kq * 8;
    else if constexpr (MODE == M_FC1) browb = Wb + (size_t)(n0 + r_) * 512 + kq * 8;
    else if constexpr (MODE == M_DELTA) browb = Wb + ((size_t)(kdel * 1024 + n0 + r_)) * 32 + kq * 8;
    else browb = (const __hip_bfloat16*)Aptr + (size_t)(bq * 256 + n0 + r_) * 512 + kq * 8;  // FC2: B = t2 bf16

    f32x4 acc[4];
    #pragma unroll
    for (int nf = 0; nf < 4; ++nf) acc[nf] = (f32x4){0.f, 0.f, 0.f, 0.f};

    for (int k0 = 0; k0 < KK; k0 += 32) {
        __syncthreads();
        if constexpr (A_COPY) {
            *adst = *(const uint4*)(arowb + k0);
        } else {
            float4 u0 = *(const float4*)(arowf + k0);
            float4 u1 = *(const float4*)(arowf + k0 + 4);
            uint4 pk; pk.x = pk2(u0.x, u0.y); pk.y = pk2(u0.z, u0.w); pk.z = pk2(u1.x, u1.y); pk.w = pk2(u1.z, u1.w);
            *adst = pk;
        }
        *bdst = *(const uint4*)(browb + k0);
        __syncthreads();
        int mrow = wv * 16 + (lane & 15);
        int ks = lane >> 4;
        bf16x8 af = *(const bf16x8*)(Asm + mrow * 32 + ((ks ^ ((mrow >> 1) & 3)) * 8));
        #pragma unroll
        for (int nf = 0; nf < 4; ++nf) {
            int nrow = nf * 16 + (lane & 15);
            bf16x8 bfv = *(const bf16x8*)(Bsm + nrow * 32 + ((ks ^ ((nrow >> 1) & 3)) * 8));
            acc[nf] = __builtin_amdgcn_mfma_f32_16x16x32_bf16(af, bfv, acc[nf], 0, 0, 0);
        }
    }

    const int mlb = (lane >> 4) * 4, nl = lane & 15;
    #pragma unroll
    for (int nf = 0; nf < 4; ++nf) {
        #pragma unroll
        for (int j = 0; j < 4; ++j) {
            float v = acc[nf][j];
            int m_loc = wv * 16 + mlb + j;
            int n_loc = nf * 16 + nl;
            if constexpr (MODE == M_INPROJ) {
                int m = m0 + m_loc, n = n0 + n_loc;
                if (n0 < 1024) O[(size_t)m * 1024 + n] = v;           // xa pos-major f32
                else O2[(size_t)m * 1024 + (n - 1024)] = v;           // z pos-major f32
            } else if constexpr (MODE == M_XDBL) {
                int m = m0 + m_loc; int b = m >> 8, l = m & 255;
                O[((size_t)(b * 4 + kdir) * 256 + l) * 64 + n_loc] = v;
            } else if constexpr (MODE == M_OUTPROJ) {
                int m = m0 + m_loc, n = n0 + n_loc; int b = m >> 8, l = m & 255;
                float f = AUX[((size_t)b * 512 + n) * 256 + l] + v;   // + residual x (NCHW)
                Ob[(size_t)m * 512 + n] = __float2bfloat16(f);        // vssb
            } else if constexpr (MODE == M_FC1) {
                int m = m0 + m_loc, n = n0 + n_loc;
                float gl = 0.5f * v * (1.f + erff(v * 0.70710678118f));
                Ob[(size_t)m * 512 + n] = __float2bfloat16(gl);       // t2 bf16
            } else if constexpr (MODE == M_DELTA) {
                int m = m0 + m_loc, n = n0 + n_loc;   // m = bk*256+l, n = d
                int bkk = m >> 8, l = m & 255;
                float v2 = v + AUX[kdel * 1024 + n];  // + dt_b
                float dlt = (v2 > 20.f) ? v2 : __logf(1.f + __expf(v2));
                O[((((size_t)bkk * 32) + (n >> 5)) * 256 + l) * 32 + (n & 31)] = dlt;  // tiled dys
            } else {  // FC2: m=c, n=l
                int c = m0 + m_loc, n = n0 + n_loc;
                O[((size_t)(bq * 512 + c)) * 256 + n] = v * AUX[bq * 512 + c];
            }
        }
    }
}

// ---------------- depthwise 3x3 + bias + SiLU; xa pos-major -> xs_t[b][j][l][1024] ----------------
__global__ __launch_bounds__(256) void k_dwconv2(const float* __restrict__ xa, const float* __restrict__ cw,
                                                 const float* __restrict__ cb, float* __restrict__ xs_t) {
    int pos = blockIdx.x;
    int b = pos >> 8, l = pos & 255;
    int h = l >> 4, w = l & 15;
    int t = threadIdx.x;
    int d = t * 4;
    float wv[36];
    {
        const float4* cp = (const float4*)(cw + (size_t)d * 9);
        #pragma unroll
        for (int j = 0; j < 9; ++j) { float4 v = cp[j]; wv[j*4] = v.x; wv[j*4+1] = v.y; wv[j*4+2] = v.z; wv[j*4+3] = v.w; }
    }
    float4 bias = *(const float4*)(cb + d);
    float a0 = bias.x, a1 = bias.y, a2 = bias.z, a3 = bias.w;
    #pragma unroll
    for (int ky = -1; ky <= 1; ++ky) {
        int hh = h + ky;
        if ((unsigned)hh >= 16u) continue;
        #pragma unroll
        for (int kx = -1; kx <= 1; ++kx) {
            int ww = w + kx;
            if ((unsigned)ww >= 16u) continue;
            float4 v = *(const float4*)(xa + (size_t)(b * 256 + hh * 16 + ww) * 1024 + d);
            int tap = (ky + 1) * 3 + (kx + 1);
            a0 = fmaf(v.x, wv[0 * 9 + tap], a0);
            a1 = fmaf(v.y, wv[1 * 9 + tap], a1);
            a2 = fmaf(v.z, wv[2 * 9 + tap], a2);
            a3 = fmaf(v.w, wv[3 * 9 + tap], a3);
        }
    }
    float4 o; o.x = siluf_(a0); o.y = siluf_(a1); o.z = siluf_(a2); o.w = siluf_(a3);
    *(float4*)(xs_t + ((size_t)(b * 2 + 0) * 256 + l) * 1024 + d) = o;
    *(float4*)(xs_t + ((size_t)(b * 2 + 1) * 256 + lmap1(l)) * 1024 + d) = o;
}

// ---------------- selective scan v7: tiled layout + native v_exp_f32 (64 VGPR, no spill) ----------------
// dys layout: [bk][db(32)][l(256)][dd(32)]
__global__ __launch_bounds__(512) void k_scan7(const float* __restrict__ xs_t, const float* __restrict__ x_dbl,
                                               const float* __restrict__ A_logs, const float* __restrict__ Ds,
                                               float* __restrict__ dys) {
    const int bk = blockIdx.x >> 5;
    const int db = blockIdx.x & 31;
    const int b = bk >> 2, k = bk & 3;
    const int t = threadIdx.x;
    const int c = t >> 5, dd = t & 31;
    const int d = db * 32 + dd;
    const bool rev = (k >= 2);

    __shared__ float Ssh[16][33];
    __shared__ float locH[16][32][17];

    float An2[16];
    {
        const float* alp = A_logs + (size_t)(k * 1024 + d) * 16;
        #pragma unroll
        for (int i = 0; i < 16; ++i) An2[i] = -__expf(alp[i]) * 1.44269504088896f;
    }
    const float Dv = Ds[k * 1024 + d];

    const int lbeg = c * 16;
    float* yp = dys + (((size_t)bk * 32 + db) * 256 + lbeg) * 32 + dd;
    const float* up = xs_t + ((size_t)(b * 2 + (k & 1)) * 256 + (rev ? 255 - lbeg : lbeg)) * 1024 + d;
    const ptrdiff_t ustr = rev ? -1024 : 1024;
    const float* xc = x_dbl + (size_t)bk * 256 * 64 + lbeg * 64;

    float h[16];
    #pragma unroll
    for (int i = 0; i < 16; ++i) h[i] = 0.f;
    float S = 0.f;

    // ---- pass 1: local scan from h=0, accumulate S = sum(delta) ----
    #pragma unroll 4
    for (int li = 0; li < 16; ++li) {
        float dl = yp[li * 32];
        float u = up[(ptrdiff_t)li * ustr];
        S += dl;
        float du = dl * u;
        #pragma unroll
        for (int q = 0; q < 4; ++q) {
            float4 Bq = *(const float4*)(xc + li * 64 + 32 + q * 4);
            h[q*4+0] = fmaf(ex2_(dl * An2[q*4+0]), h[q*4+0], du * Bq.x);
            h[q*4+1] = fmaf(ex2_(dl * An2[q*4+1]), h[q*4+1], du * Bq.y);
            h[q*4+2] = fmaf(ex2_(dl * An2[q*4+2]), h[q*4+2], du * Bq.z);
            h[q*4+3] = fmaf(ex2_(dl * An2[q*4+3]), h[q*4+3], du * Bq.w);
        }
    }
    Ssh[c][dd] = S;
    #pragma unroll
    for (int i = 0; i < 16; ++i) locH[c][dd][i] = h[i];
    __syncthreads();

    // ---- middle: compose preceding chunks in order ----
    #pragma unroll
    for (int i = 0; i < 16; ++i) h[i] = 0.f;
    for (int j = 0; j < c; ++j) {
        float Sj = Ssh[j][dd];
        #pragma unroll
        for (int i = 0; i < 16; ++i) h[i] = fmaf(ex2_(Sj * An2[i]), h[i], locH[j][dd][i]);
    }

    // ---- pass 2: re-scan from correct h_start, emit ys ----
    #pragma unroll 4
    for (int li = 0; li < 16; ++li) {
        float dl = yp[li * 32];
        float u = up[(ptrdiff_t)li * ustr];
        float du = dl * u;
        float yv = 0.f;
        #pragma unroll
        for (int q = 0; q < 4; ++q) {
            float4 Bq = *(const float4*)(xc + li * 64 + 32 + q * 4);
            float4 Cq = *(const float4*)(xc + li * 64 + 48 + q * 4);
            h[q*4+0] = fmaf(ex2_(dl * An2[q*4+0]), h[q*4+0], du * Bq.x); yv = fmaf(h[q*4+0], Cq.x, yv);
            h[q*4+1] = fmaf(ex2_(dl * An2[q*4+1]), h[q*4+1], du * Bq.y); yv = fmaf(h[q*4+1], Cq.y, yv);
            h[q*4+2] = fmaf(ex2_(dl * An2[q*4+2]), h[q*4+2], du * Bq.z); yv = fmaf(h[q*4+2], Cq.z, yv);
            h[q*4+3] = fmaf(ex2_(dl * An2[q*4+3]), h[q*4+3], du * Bq.w); yv = fmaf(h[q*4+3], Cq.w, yv);
        }
        yp[li * 32] = yv + u * Dv;
    }
}

// ---------------- combine 4 dirs + out_norm LN + silu(z) -> yc bf16 pos-major ----------------
__global__ __launch_bounds__(256) void k_combine(const float* __restrict__ dys, const float* __restrict__ z,
                                                 const float* __restrict__ g, const float* __restrict__ bb,
                                                 __hip_bfloat16* __restrict__ ycb) {
    int pos = blockIdx.x;
    int b = pos >> 8, l = pos & 255;
    int t = threadIdx.x;
    int lw = lmap1(l);
    int db0 = t >> 5, dd = t & 31;
    float v[4];
    float psum = 0.f;
    #pragma unroll
    for (int q = 0; q < 4; ++q) {
        int dbq = db0 + q * 8;
        float s0 = dys[((((size_t)(b * 4 + 0) * 32) + dbq) * 256 + l) * 32 + dd];
        float s1 = dys[((((size_t)(b * 4 + 1) * 32) + dbq) * 256 + lw) * 32 + dd];
        float s2 = dys[((((size_t)(b * 4 + 2) * 32) + dbq) * 256 + (255 - l)) * 32 + dd];
        float s3 = dys[((((size_t)(b * 4 + 3) * 32) + dbq) * 256 + (255 - lw)) * 32 + dd];
        v[q] = s0 + s1 + s2 + s3;
        psum += v[q];
    }
    __shared__ float red[256];
    red[t] = psum;
    __syncthreads();
    for (int s = 128; s > 0; s >>= 1) { if (t < s) red[t] += red[t + s]; __syncthreads(); }
    float mu = red[0] * (1.f / 1024.f);
    __syncthreads();
    float p2 = 0.f;
    #pragma unroll
    for (int q = 0; q < 4; ++q) { float ddv = v[q] - mu; p2 += ddv * ddv; }
    red[t] = p2;
    __syncthreads();
    for (int s = 128; s > 0; s >>= 1) { if (t < s) red[t] += red[t + s]; __syncthreads(); }
    float rs = rsqrtf(red[0] * (1.f / 1024.f) + EPS_);
    #pragma unroll
    for (int q = 0; q < 4; ++q) {
        int d = (db0 + q * 8) * 32 + dd;
        float zn = z[(size_t)pos * 1024 + d];
        float o = ((v[q] - mu) * rs * g[d] + bb[d]) * siluf_(zn);
        ycb[(size_t)pos * 1024 + d] = __float2bfloat16(o);
    }
}

// ---------------- implicit-GEMM 3x3 conv via bf16 MFMA, 8-way K-split over ci ----------------
__global__ __launch_bounds__(256) void k_conv2m(const __hip_bfloat16* __restrict__ vssb,
                                                const __hip_bfloat16* __restrict__ wt,
                                                float* __restrict__ convp) {
    __shared__ short Asm[18 * 18 * 32];
    __shared__ short Bsm[9 * 64 * 32];
    const int b = blockIdx.x, co0 = blockIdx.y * 64, split = blockIdx.z;  // split 0..7
    const int t = threadIdx.x;
    const int lane = t & 63, wid = t >> 6;
    const int wcol = lane & 15, slot = lane >> 4;

    f32x4 acc[4][4];
    #pragma unroll
    for (int r = 0; r < 4; ++r)
        #pragma unroll
        for (int g = 0; g < 4; ++g) acc[r][g] = (f32x4){0.f, 0.f, 0.f, 0.f};

    for (int ch = 0; ch < 2; ++ch) {
        const int ci0 = split * 64 + ch * 32;
        __syncthreads();
        for (int i = t; i < 324; i += 256) {
            int row = i / 18, col = i - row * 18;
            uint4 v0 = {0,0,0,0}, v1 = {0,0,0,0}, v2 = {0,0,0,0}, v3 = {0,0,0,0};
            if (row >= 1 && row <= 16 && col >= 1 && col <= 16) {
                const uint4* src = (const uint4*)(vssb + ((size_t)(b * 256 + (row - 1) * 16 + (col - 1)) * 512 + ci0));
                v0 = src[0]; v1 = src[1]; v2 = src[2]; v3 = src[3];
            }
            uint4* dst = (uint4*)(Asm + i * 32);
            int key = (col >> 1) & 3;
            dst[0 ^ key] = v0; dst[1 ^ key] = v1; dst[2 ^ key] = v2; dst[3 ^ key] = v3;
        }
        for (int i = t; i < 576; i += 256) {
            int tap = i >> 6, col = i & 63;
            const uint4* src = (const uint4*)(wt + ((size_t)(tap * 512 + co0 + col) * 512 + ci0));
            uint4* dst = (uint4*)(Bsm + i * 32);
            int key = (col >> 1) & 3;
            dst[0 ^ key] = src[0]; dst[1 ^ key] = src[1]; dst[2 ^ key] = src[2]; dst[3 ^ key] = src[3];
        }
        __syncthreads();
        #pragma unroll
        for (int tap = 0; tap < 9; ++tap) {
            const int ky = tap / 3, kx = tap - ky * 3;
            bf16x8 af[4], bfr[4];
            #pragma unroll
            for (int r = 0; r < 4; ++r) {
                int crow = wid * 4 + r + ky;
                int ccol = wcol + kx;
                int s2 = slot ^ ((ccol >> 1) & 3);
                af[r] = *(const bf16x8*)(Asm + ((crow * 18 + ccol) * 32 + s2 * 8));
            }
            #pragma unroll
            for (int g = 0; g < 4; ++g) {
                int col = g * 16 + wcol;
                int s2 = slot ^ ((col >> 1) & 3);
                bfr[g] = *(const bf16x8*)(Bsm + ((tap * 64 + col) * 32 + s2 * 8));
            }
            #pragma unroll
            for (int r = 0; r < 4; ++r)
                #pragma unroll
                for (int g = 0; g < 4; ++g)
                    acc[r][g] = __builtin_amdgcn_mfma_f32_16x16x32_bf16(af[r], bfr[g], acc[r][g], 0, 0, 0);
        }
    }
    float* base = convp + (size_t)split * 1048576 + (size_t)b * 512 * 256;
    #pragma unroll
    for (int r = 0; r < 4; ++r) {
        int h = wid * 4 + r;
        #pragma unroll
        for (int g = 0; g < 4; ++g) {
            int co = co0 + g * 16 + wcol;
            *(f32x4*)(base + (size_t)co * 256 + h * 16 + slot * 4) = acc[r][g];
        }
    }
}

// ---------------- reduce 8 K-splits + BN + relu6 -> t1 bf16 POS-MAJOR [b*256+pos][512] ----------------
__global__ __launch_bounds__(256) void k_convred2(const float* __restrict__ convp,
                                                  const float* __restrict__ bn_g, const float* __restrict__ bn_b,
                                                  const float* __restrict__ bn_mean, const float* __restrict__ bn_var,
                                                  __hip_bfloat16* __restrict__ t1b) {
    int b = blockIdx.x >> 7, cb = (blockIdx.x >> 3) & 15, pb = blockIdx.x & 7;
    int co0 = cb * 32, pos0 = pb * 32;
    int t = threadIdx.x;
    int ti = t >> 5, tj = t & 31;
    __shared__ float tile[32][33];
    #pragma unroll
    for (int r = 0; r < 4; ++r) {
        int co = co0 + ti + r * 8;
        size_t idx = ((size_t)b * 512 + co) * 256 + pos0 + tj;
        float s = 0.f;
        #pragma unroll
        for (int sp = 0; sp < 8; ++sp) s += convp[idx + (size_t)sp * 1048576];
        float o = (s - bn_mean[co]) * rsqrtf(bn_var[co] + EPS_) * bn_g[co] + bn_b[co];
        tile[ti + r * 8][tj] = fminf(fmaxf(o, 0.f), 6.f);
    }
    __syncthreads();
    #pragma unroll
    for (int r = 0; r < 4; ++r) {
        int pos = pos0 + ti + r * 8;
        t1b[((size_t)b * 256 + pos) * 512 + co0 + tj] = __float2bfloat16(tile[tj][ti + r * 8]);
    }
}

extern "C" void kernel_launch(void* const* d_in, const int* in_sizes, int n_in,
                              void* d_out, int out_size, void* d_ws, size_t ws_size,
                              hipStream_t stream) {
    const float* x = (const float*)d_in[0];
    const float* y = (const float*)d_in[1];
    const float* ln1_g = (const float*)d_in[2];
    const float* ln1_b = (const float*)d_in[3];
    const float* in_proj_w = (const float*)d_in[4];
    const float* conv_w = (const float*)d_in[5];
    const float* conv_b = (const float*)d_in[6];
    const float* x_proj_w = (const float*)d_in[7];
    const float* dt_w = (const float*)d_in[8];
    const float* dt_b = (const float*)d_in[9];
    const float* A_logs = (const float*)d_in[10];
    const float* Ds = (const float*)d_in[11];
    const float* out_norm_g = (const float*)d_in[12];
    const float* out_norm_b = (const float*)d_in[13];
    const float* out_proj_w = (const float*)d_in[14];
    const float* ffn_conv_w = (const float*)d_in[15];
    const float* bn_g = (const float*)d_in[16];
    const float* bn_b = (const float*)d_in[17];
    const float* bn_mean = (const float*)d_in[18];
    const float* bn_var = (const float*)d_in[19];
    const float* fc1_w = (const float*)d_in[20];
    const float* fc2_w = (const float*)d_in[21];
    const float* lin1_w = (const float*)d_in[22];
    const float* lin1_b = (const float*)d_in[23];
    const float* lin2_w = (const float*)d_in[24];
    const float* lin2_b = (const float*)d_in[25];
    float* out = (float*)d_out;

    char* ws = (char*)d_ws;
    size_t off = 0;
    auto alloc = [&](size_t nf) { float* p = (float*)(ws + off); off += nf * sizeof(float); return p; };
    float* xn    = alloc(2048u * 512);        // 4MB; xnb bf16 (2MB), then vssb bf16 (2MB)
    float* xa    = alloc(2048u * 1024);       // 8MB f32 pos-major; then ycb bf16 (4MB)
    float* z     = alloc(2048u * 1024);       // 8MB z pos-major f32
    float* xs_t  = alloc(2u * 2048 * 1024);   // 16MB f32; then t1b bf16 (2MB) + t2b bf16 (2MB)
    float* x_dbl = alloc(8u * 4 * 256 * 64);  // 2MB
    float* ys_t  = alloc(4u * 2048 * 1024);   // 32MB; tiled delta/ys; then convp (32MB)
    float* wb    = alloc(2424832);            // 9.25MB bf16 weights (7 tensors incl. ffn conv)
    float* pooled = alloc(4096);
    float* gate   = alloc(4096);

    __hip_bfloat16* xnb = (__hip_bfloat16*)xn;
    __hip_bfloat16* vssb = (__hip_bfloat16*)xn;         // after xnb dead
    __hip_bfloat16* ycb = (__hip_bfloat16*)xa;          // after xa f32 dead
    __hip_bfloat16* t1b = (__hip_bfloat16*)xs_t;        // after scan done
    __hip_bfloat16* t2b = (__hip_bfloat16*)(xs_t + 2048u * 512);
    float* convp = ys_t;
    __hip_bfloat16* inprojb = (__hip_bfloat16*)wb;
    __hip_bfloat16* xprojb  = inprojb + 1048576;
    __hip_bfloat16* outprojb = xprojb + 262144;
    __hip_bfloat16* fc1b = outprojb + 524288;
    __hip_bfloat16* fc2b = fc1b + 262144;
    __hip_bfloat16* dtwb = fc2b + 262144;
    __hip_bfloat16* w_t  = dtwb + 131072;               // ffn conv weights, dedicated

    k_wcast6<<<3456, 256, 0, stream>>>(in_proj_w, x_proj_w, out_proj_w, fc1_w, fc2_w, dt_w, ffn_conv_w, inprojb);
    k_pool<<<4096, 256, 0, stream>>>(y, pooled);
    k_gate<<<8, 256, 0, stream>>>(pooled, lin1_w, lin1_b, lin2_w, lin2_b, gate);
    k_ln<<<2048, 256, 0, stream>>>(x, ln1_g, ln1_b, xnb);
    gemm_mfma<M_INPROJ><<<dim3(32, 32), 256, 0, stream>>>(xnb, inprojb, xa, z, nullptr, nullptr);
    k_dwconv2<<<2048, 256, 0, stream>>>(xa, conv_w, conv_b, xs_t);
    gemm_mfma<M_XDBL><<<dim3(32, 4), 256, 0, stream>>>(xs_t, xprojb, x_dbl, nullptr, nullptr, nullptr);
    gemm_mfma<M_DELTA><<<dim3(128, 16), 256, 0, stream>>>(x_dbl, dtwb, ys_t, nullptr, dt_b, nullptr);
    k_scan7<<<1024, 512, 0, stream>>>(xs_t, x_dbl, A_logs, Ds, ys_t);
    k_combine<<<2048, 256, 0, stream>>>(ys_t, z, out_norm_g, out_norm_b, ycb);
    gemm_mfma<M_OUTPROJ><<<dim3(32, 8), 256, 0, stream>>>(ycb, outprojb, nullptr, nullptr, x, vssb);
    k_conv2m<<<dim3(8, 8, 8), 256, 0, stream>>>(vssb, w_t, convp);
    k_convred2<<<1024, 256, 0, stream>>>(convp, bn_g, bn_b, bn_mean, bn_var, t1b);
    gemm_mfma<M_FC1><<<dim3(32, 8), 256, 0, stream>>>(t1b, fc1b, nullptr, nullptr, nullptr, t2b);
    gemm_mfma<M_FC2><<<dim3(64, 4), 256, 0, stream>>>(t2b, fc2b, out, nullptr, gate, nullptr);
}

// Round 14
// 244.470 us; speedup vs baseline: 1.3384x; 1.0111x over previous
//
#include <hip/hip_runtime.h>
#include <hip/hip_bf16.h>
#include <math.h>

#define DEV_INLINE __device__ __forceinline__

constexpr int B_ = 8, C_ = 512, L_ = 256;
constexpr float EPS_ = 1e-5f;

typedef __attribute__((ext_vector_type(8))) short bf16x8;
typedef __attribute__((ext_vector_type(4))) float f32x4;

DEV_INLINE int lmap1(int l) { return ((l & 15) << 4) | (l >> 4); }
DEV_INLINE float sigmoidf_(float x) { return 1.f / (1.f + __expf(-x)); }
DEV_INLINE float siluf_(float x) { return x * sigmoidf_(x); }
DEV_INLINE float ex2_(float x) { return __builtin_amdgcn_exp2f(x); }
DEV_INLINE float b2f(__hip_bfloat16 v) { return __bfloat162float(v); }

DEV_INLINE unsigned pk2(float a, float b) {
    __hip_bfloat16 x = __float2bfloat16(a), y = __float2bfloat16(b);
    unsigned short ux = *reinterpret_cast<unsigned short*>(&x);
    unsigned short uy = *reinterpret_cast<unsigned short*>(&y);
    return ((unsigned)uy << 16) | ux;
}

// ---------------- prologue: weight casts + LN + pooled-gate, one launch ----------------
// blocks 0..2431: 6 GEMM weights -> wb; 2432..3455: ffn_conv_w -> wtb;
// 3456..5503: LayerNorm (pos = bid-3456) -> xnb bf16; 5504..5511: pool+gate (b = bid-5504)
__global__ __launch_bounds__(256) void k_prologue(const float* __restrict__ ip, const float* __restrict__ xp,
                                                  const float* __restrict__ op, const float* __restrict__ f1,
                                                  const float* __restrict__ f2, const float* __restrict__ dtw,
                                                  const float* __restrict__ fw, __hip_bfloat16* __restrict__ dst,
                                                  const float* __restrict__ x, const float* __restrict__ ln_g,
                                                  const float* __restrict__ ln_b, __hip_bfloat16* __restrict__ xnb,
                                                  const float* __restrict__ y,
                                                  const float* __restrict__ lin1_w, const float* __restrict__ lin1_b,
                                                  const float* __restrict__ lin2_w, const float* __restrict__ lin2_b,
                                                  float* __restrict__ gate) {
    const int bid = blockIdx.x;
    const int t = threadIdx.x;
    __shared__ float sh[768];
    if (bid < 2432) {
        size_t e = ((size_t)bid * 256 + t) * 4;
        const float* src; size_t off;
        if (e < 1048576) { src = ip; off = e; }
        else if (e < 1310720) { src = xp; off = e - 1048576; }
        else if (e < 1835008) { src = op; off = e - 1310720; }
        else if (e < 2097152) { src = f1; off = e - 1835008; }
        else if (e < 2359296) { src = f2; off = e - 2097152; }
        else { src = dtw; off = e - 2359296; }
        float4 v = *(const float4*)(src + off);
        uint2 o; o.x = pk2(v.x, v.y); o.y = pk2(v.z, v.w);
        *(uint2*)(dst + e) = o;
    } else if (bid < 3456) {
        int gid = (bid - 2432) * 256 + t;  // co*512+ci
        __hip_bfloat16* wt = dst + 2490368;
        const float* src = fw + (size_t)gid * 9;
        #pragma unroll
        for (int tap = 0; tap < 9; ++tap) wt[(size_t)tap * 262144 + gid] = __float2bfloat16(src[tap]);
    } else if (bid < 5504) {
        int pos = bid - 3456;
        int b = pos >> 8, l = pos & 255;
        float v0 = x[(b * C_ + t) * L_ + l];
        float v1 = x[(b * C_ + t + 256) * L_ + l];
        float* red = sh;
        red[t] = v0 + v1;
        __syncthreads();
        for (int s = 128; s > 0; s >>= 1) { if (t < s) red[t] += red[t + s]; __syncthreads(); }
        float mu = red[0] * (1.f / 512.f);
        __syncthreads();
        float d0 = v0 - mu, d1 = v1 - mu;
        red[t] = d0 * d0 + d1 * d1;
        __syncthreads();
        for (int s = 128; s > 0; s >>= 1) { if (t < s) red[t] += red[t + s]; __syncthreads(); }
        float rs = rsqrtf(red[0] * (1.f / 512.f) + EPS_);
        xnb[pos * C_ + t] = __float2bfloat16(d0 * rs * ln_g[t] + ln_b[t]);
        xnb[pos * C_ + t + 256] = __float2bfloat16(d1 * rs * ln_g[t + 256] + ln_b[t + 256]);
    } else {
        int b = bid - 5504;
        float* p = sh;          // [512]
        float* h1 = sh + 512;   // [256]
        // pooled for channels t and t+256 (each thread sums its own 1KB row)
        #pragma unroll
        for (int cc = 0; cc < 2; ++cc) {
            int cch = t + cc * 256;
            const float4* yp = (const float4*)(y + (size_t)(b * 512 + cch) * 256);
            float s = 0.f;
            #pragma unroll 4
            for (int j = 0; j < 64; ++j) { float4 v = yp[j]; s += v.x + v.y + v.z + v.w; }
            p[cch] = s * (1.f / 256.f);
        }
        __syncthreads();
        float s = lin1_b[t];
        const float4* wp1 = (const float4*)(lin1_w + t * 512);
        #pragma unroll 4
        for (int c = 0; c < 128; ++c) {
            float4 pv = *(const float4*)(p + c * 4);
            float4 wv = wp1[c];
            s = fmaf(pv.x, wv.x, s); s = fmaf(pv.y, wv.y, s);
            s = fmaf(pv.z, wv.z, s); s = fmaf(pv.w, wv.w, s);
        }
        h1[t] = fmaxf(s, 0.f);
        __syncthreads();
        #pragma unroll
        for (int cc = 0; cc < 2; ++cc) {
            int c = t + cc * 256;
            float s2 = lin2_b[c];
            const float4* wp2 = (const float4*)(lin2_w + c * 256);
            #pragma unroll 4
            for (int j = 0; j < 64; ++j) {
                float4 hv = *(const float4*)(h1 + j * 4);
                float4 wv = wp2[j];
                s2 = fmaf(hv.x, wv.x, s2); s2 = fmaf(hv.y, wv.y, s2);
                s2 = fmaf(hv.z, wv.z, s2); s2 = fmaf(hv.w, wv.w, s2);
            }
            gate[b * 512 + c] = sigmoidf_(2.f * s2);
        }
    }
}

// ---------------- unified bf16-MFMA GEMM, 64x64 tile, BK=32, fused epilogues ----------------
enum { M_INPROJ = 0, M_XDBL = 1, M_OUTPROJ = 2, M_FC1 = 3, M_FC2 = 4, M_DELTA = 5 };

template <int MODE>
__global__ __launch_bounds__(256) void gemm_mfma(const void* __restrict__ Aptr, const __hip_bfloat16* __restrict__ Wb,
                                                 float* __restrict__ O, float* __restrict__ O2,
                                                 const float* __restrict__ AUX, __hip_bfloat16* __restrict__ Ob) {
    constexpr int KK = (MODE == M_XDBL || MODE == M_OUTPROJ) ? 1024 : (MODE == M_DELTA) ? 32 : 512;
    constexpr bool A_COPY = (MODE != M_DELTA);
    __shared__ short Asm[64 * 32];
    __shared__ short Bsm[64 * 32];
    const int t = threadIdx.x;
    const int lane = t & 63, wv = t >> 6;
    int m0, n0 = 0, kdir = 0, bq = 0;
    if constexpr (MODE == M_XDBL) { m0 = blockIdx.x * 64; kdir = blockIdx.y; }
    else if constexpr (MODE == M_FC2) { bq = blockIdx.x >> 3; m0 = (blockIdx.x & 7) * 64; n0 = blockIdx.y * 64; }
    else { m0 = blockIdx.x * 64; n0 = blockIdx.y * 64; }
    const int kdel = (m0 >> 8) & 3;  // bk's k for M_DELTA

    const int r_ = t >> 2, kq = t & 3;
    const int skey = (r_ >> 1) & 3;
    uint4* adst = (uint4*)(Asm + r_ * 32) + (kq ^ skey);
    uint4* bdst = (uint4*)(Bsm + r_ * 32) + (kq ^ skey);

    // ---- A-side source row ----
    const float* arowf = nullptr;
    const __hip_bfloat16* arowb = nullptr;
    if constexpr (MODE == M_INPROJ) arowb = (const __hip_bfloat16*)Aptr + (size_t)(m0 + r_) * 512 + kq * 8;
    else if constexpr (MODE == M_XDBL) {
        int m = m0 + r_; int b = m >> 8, l = m & 255;
        int lm = (kdir < 2) ? l : 255 - l;
        arowb = (const __hip_bfloat16*)Aptr + (size_t)((b * 2 + (kdir & 1)) * 256 + lm) * 1024 + kq * 8;
    } else if constexpr (MODE == M_OUTPROJ) arowb = (const __hip_bfloat16*)Aptr + (size_t)(m0 + r_) * 1024 + kq * 8;
    else if constexpr (MODE == M_FC1) arowb = (const __hip_bfloat16*)Aptr + (size_t)(m0 + r_) * 512 + kq * 8;
    else if constexpr (MODE == M_DELTA) arowf = (const float*)Aptr + (size_t)(m0 + r_) * 64 + kq * 8;
    else arowb = Wb + (size_t)(m0 + r_) * 512 + kq * 8;  // FC2: A = fc2 weights bf16

    // ---- B-side source row (always bf16) ----
    const __hip_bfloat16* browb = nullptr;
    if constexpr (MODE == M_INPROJ) browb = Wb + (size_t)(n0 + r_) * 512 + kq * 8;
    else if constexpr (MODE == M_XDBL) browb = Wb + (size_t)(kdir * 64 + r_) * 1024 + kq * 8;
    else if constexpr (MODE == M_OUTPROJ) browb = Wb + (size_t)(n0 + r_) * 1024 + kq * 8;
    else if constexpr (MODE == M_FC1) browb = Wb + (size_t)(n0 + r_) * 512 + kq * 8;
    else if constexpr (MODE == M_DELTA) browb = Wb + ((size_t)(kdel * 1024 + n0 + r_)) * 32 + kq * 8;
    else browb = (const __hip_bfloat16*)Aptr + (size_t)(bq * 256 + n0 + r_) * 512 + kq * 8;  // FC2: B = t2 bf16

    f32x4 acc[4];
    #pragma unroll
    for (int nf = 0; nf < 4; ++nf) acc[nf] = (f32x4){0.f, 0.f, 0.f, 0.f};

    for (int k0 = 0; k0 < KK; k0 += 32) {
        __syncthreads();
        if constexpr (A_COPY) {
            *adst = *(const uint4*)(arowb + k0);
        } else {
            float4 u0 = *(const float4*)(arowf + k0);
            float4 u1 = *(const float4*)(arowf + k0 + 4);
            uint4 pk; pk.x = pk2(u0.x, u0.y); pk.y = pk2(u0.z, u0.w); pk.z = pk2(u1.x, u1.y); pk.w = pk2(u1.z, u1.w);
            *adst = pk;
        }
        *bdst = *(const uint4*)(browb + k0);
        __syncthreads();
        int mrow = wv * 16 + (lane & 15);
        int ks = lane >> 4;
        bf16x8 af = *(const bf16x8*)(Asm + mrow * 32 + ((ks ^ ((mrow >> 1) & 3)) * 8));
        #pragma unroll
        for (int nf = 0; nf < 4; ++nf) {
            int nrow = nf * 16 + (lane & 15);
            bf16x8 bfv = *(const bf16x8*)(Bsm + nrow * 32 + ((ks ^ ((nrow >> 1) & 3)) * 8));
            acc[nf] = __builtin_amdgcn_mfma_f32_16x16x32_bf16(af, bfv, acc[nf], 0, 0, 0);
        }
    }

    const int mlb = (lane >> 4) * 4, nl = lane & 15;
    #pragma unroll
    for (int nf = 0; nf < 4; ++nf) {
        #pragma unroll
        for (int j = 0; j < 4; ++j) {
            float v = acc[nf][j];
            int m_loc = wv * 16 + mlb + j;
            int n_loc = nf * 16 + nl;
            if constexpr (MODE == M_INPROJ) {
                int m = m0 + m_loc, n = n0 + n_loc;
                if (n0 < 1024) Ob[(size_t)m * 1024 + n] = __float2bfloat16(v);                  // xab bf16
                else ((__hip_bfloat16*)O2)[(size_t)m * 1024 + (n - 1024)] = __float2bfloat16(v); // zb bf16
            } else if constexpr (MODE == M_XDBL) {
                int m = m0 + m_loc; int b = m >> 8, l = m & 255;
                O[((size_t)(b * 4 + kdir) * 256 + l) * 64 + n_loc] = v;
            } else if constexpr (MODE == M_OUTPROJ) {
                int m = m0 + m_loc, n = n0 + n_loc; int b = m >> 8, l = m & 255;
                float f = AUX[((size_t)b * 512 + n) * 256 + l] + v;   // + residual x (NCHW)
                Ob[(size_t)m * 512 + n] = __float2bfloat16(f);        // vssb
            } else if constexpr (MODE == M_FC1) {
                int m = m0 + m_loc, n = n0 + n_loc;
                float gl = 0.5f * v * (1.f + erff(v * 0.70710678118f));
                Ob[(size_t)m * 512 + n] = __float2bfloat16(gl);       // t2 bf16
            } else if constexpr (MODE == M_DELTA) {
                int m = m0 + m_loc, n = n0 + n_loc;   // m = bk*256+l, n = d
                int bkk = m >> 8, l = m & 255;
                float v2 = v + AUX[kdel * 1024 + n];  // + dt_b
                float dlt = (v2 > 20.f) ? v2 : __logf(1.f + __expf(v2));
                O[((((size_t)bkk * 32) + (n >> 5)) * 256 + l) * 32 + (n & 31)] = dlt;  // tiled dys
            } else {  // FC2: m=c, n=l
                int c = m0 + m_loc, n = n0 + n_loc;
                O[((size_t)(bq * 512 + c)) * 256 + n] = v * AUX[bq * 512 + c];
            }
        }
    }
}

// ---------------- depthwise 3x3 + bias + SiLU; xab bf16 pos-major -> xsb bf16 [b][j][l][1024] ----------------
__global__ __launch_bounds__(256) void k_dwconv2(const __hip_bfloat16* __restrict__ xab, const float* __restrict__ cw,
                                                 const float* __restrict__ cb, __hip_bfloat16* __restrict__ xsb) {
    int pos = blockIdx.x;
    int b = pos >> 8, l = pos & 255;
    int h = l >> 4, w = l & 15;
    int t = threadIdx.x;
    int d = t * 4;
    float wv[36];
    {
        const float4* cp = (const float4*)(cw + (size_t)d * 9);
        #pragma unroll
        for (int j = 0; j < 9; ++j) { float4 v = cp[j]; wv[j*4] = v.x; wv[j*4+1] = v.y; wv[j*4+2] = v.z; wv[j*4+3] = v.w; }
    }
    float4 bias = *(const float4*)(cb + d);
    float a0 = bias.x, a1 = bias.y, a2 = bias.z, a3 = bias.w;
    #pragma unroll
    for (int ky = -1; ky <= 1; ++ky) {
        int hh = h + ky;
        if ((unsigned)hh >= 16u) continue;
        #pragma unroll
        for (int kx = -1; kx <= 1; ++kx) {
            int ww = w + kx;
            if ((unsigned)ww >= 16u) continue;
            uint2 rv = *(const uint2*)(xab + (size_t)(b * 256 + hh * 16 + ww) * 1024 + d);
            const __hip_bfloat16* pv = (const __hip_bfloat16*)&rv;
            int tap = (ky + 1) * 3 + (kx + 1);
            a0 = fmaf(b2f(pv[0]), wv[0 * 9 + tap], a0);
            a1 = fmaf(b2f(pv[1]), wv[1 * 9 + tap], a1);
            a2 = fmaf(b2f(pv[2]), wv[2 * 9 + tap], a2);
            a3 = fmaf(b2f(pv[3]), wv[3 * 9 + tap], a3);
        }
    }
    uint2 ov; ov.x = pk2(siluf_(a0), siluf_(a1)); ov.y = pk2(siluf_(a2), siluf_(a3));
    *(uint2*)(xsb + ((size_t)(b * 2 + 0) * 256 + l) * 1024 + d) = ov;
    *(uint2*)(xsb + ((size_t)(b * 2 + 1) * 256 + lmap1(l)) * 1024 + d) = ov;
}

// ---------------- selective scan v7b: tiled dys layout, native exp, bf16 u ----------------
// dys layout: [bk][db(32)][l(256)][dd(32)]
__global__ __launch_bounds__(512) void k_scan7(const __hip_bfloat16* __restrict__ xsb, const float* __restrict__ x_dbl,
                                               const float* __restrict__ A_logs, const float* __restrict__ Ds,
                                               float* __restrict__ dys) {
    const int bk = blockIdx.x >> 5;
    const int db = blockIdx.x & 31;
    const int b = bk >> 2, k = bk & 3;
    const int t = threadIdx.x;
    const int c = t >> 5, dd = t & 31;
    const int d = db * 32 + dd;
    const bool rev = (k >= 2);

    __shared__ float Ssh[16][33];
    __shared__ float locH[16][32][17];

    float An2[16];
    {
        const float* alp = A_logs + (size_t)(k * 1024 + d) * 16;
        #pragma unroll
        for (int i = 0; i < 16; ++i) An2[i] = -__expf(alp[i]) * 1.44269504088896f;
    }
    const float Dv = Ds[k * 1024 + d];

    const int lbeg = c * 16;
    float* yp = dys + (((size_t)bk * 32 + db) * 256 + lbeg) * 32 + dd;
    const __hip_bfloat16* up = xsb + ((size_t)(b * 2 + (k & 1)) * 256 + (rev ? 255 - lbeg : lbeg)) * 1024 + d;
    const ptrdiff_t ustr = rev ? -1024 : 1024;
    const float* xc = x_dbl + (size_t)bk * 256 * 64 + lbeg * 64;

    float h[16];
    #pragma unroll
    for (int i = 0; i < 16; ++i) h[i] = 0.f;
    float S = 0.f;

    // ---- pass 1: local scan from h=0, accumulate S = sum(delta) ----
    #pragma unroll 4
    for (int li = 0; li < 16; ++li) {
        float dl = yp[li * 32];
        float u = b2f(up[(ptrdiff_t)li * ustr]);
        S += dl;
        float du = dl * u;
        #pragma unroll
        for (int q = 0; q < 4; ++q) {
            float4 Bq = *(const float4*)(xc + li * 64 + 32 + q * 4);
            h[q*4+0] = fmaf(ex2_(dl * An2[q*4+0]), h[q*4+0], du * Bq.x);
            h[q*4+1] = fmaf(ex2_(dl * An2[q*4+1]), h[q*4+1], du * Bq.y);
            h[q*4+2] = fmaf(ex2_(dl * An2[q*4+2]), h[q*4+2], du * Bq.z);
            h[q*4+3] = fmaf(ex2_(dl * An2[q*4+3]), h[q*4+3], du * Bq.w);
        }
    }
    Ssh[c][dd] = S;
    #pragma unroll
    for (int i = 0; i < 16; ++i) locH[c][dd][i] = h[i];
    __syncthreads();

    // ---- middle: compose preceding chunks in order ----
    #pragma unroll
    for (int i = 0; i < 16; ++i) h[i] = 0.f;
    for (int j = 0; j < c; ++j) {
        float Sj = Ssh[j][dd];
        #pragma unroll
        for (int i = 0; i < 16; ++i) h[i] = fmaf(ex2_(Sj * An2[i]), h[i], locH[j][dd][i]);
    }

    // ---- pass 2: re-scan from correct h_start, emit ys ----
    #pragma unroll 4
    for (int li = 0; li < 16; ++li) {
        float dl = yp[li * 32];
        float u = b2f(up[(ptrdiff_t)li * ustr]);
        float du = dl * u;
        float yv = 0.f;
        #pragma unroll
        for (int q = 0; q < 4; ++q) {
            float4 Bq = *(const float4*)(xc + li * 64 + 32 + q * 4);
            float4 Cq = *(const float4*)(xc + li * 64 + 48 + q * 4);
            h[q*4+0] = fmaf(ex2_(dl * An2[q*4+0]), h[q*4+0], du * Bq.x); yv = fmaf(h[q*4+0], Cq.x, yv);
            h[q*4+1] = fmaf(ex2_(dl * An2[q*4+1]), h[q*4+1], du * Bq.y); yv = fmaf(h[q*4+1], Cq.y, yv);
            h[q*4+2] = fmaf(ex2_(dl * An2[q*4+2]), h[q*4+2], du * Bq.z); yv = fmaf(h[q*4+2], Cq.z, yv);
            h[q*4+3] = fmaf(ex2_(dl * An2[q*4+3]), h[q*4+3], du * Bq.w); yv = fmaf(h[q*4+3], Cq.w, yv);
        }
        yp[li * 32] = yv + u * Dv;
    }
}

// ---------------- combine 4 dirs + out_norm LN + silu(z bf16) -> ycb bf16 pos-major ----------------
__global__ __launch_bounds__(256) void k_combine(const float* __restrict__ dys, const __hip_bfloat16* __restrict__ zb,
                                                 const float* __restrict__ g, const float* __restrict__ bb,
                                                 __hip_bfloat16* __restrict__ ycb) {
    int pos = blockIdx.x;
    int b = pos >> 8, l = pos & 255;
    int t = threadIdx.x;
    int lw = lmap1(l);
    int db0 = t >> 5, dd = t & 31;
    float v[4];
    float psum = 0.f;
    #pragma unroll
    for (int q = 0; q < 4; ++q) {
        int dbq = db0 + q * 8;
        float s0 = dys[((((size_t)(b * 4 + 0) * 32) + dbq) * 256 + l) * 32 + dd];
        float s1 = dys[((((size_t)(b * 4 + 1) * 32) + dbq) * 256 + lw) * 32 + dd];
        float s2 = dys[((((size_t)(b * 4 + 2) * 32) + dbq) * 256 + (255 - l)) * 32 + dd];
        float s3 = dys[((((size_t)(b * 4 + 3) * 32) + dbq) * 256 + (255 - lw)) * 32 + dd];
        v[q] = s0 + s1 + s2 + s3;
        psum += v[q];
    }
    __shared__ float red[256];
    red[t] = psum;
    __syncthreads();
    for (int s = 128; s > 0; s >>= 1) { if (t < s) red[t] += red[t + s]; __syncthreads(); }
    float mu = red[0] * (1.f / 1024.f);
    __syncthreads();
    float p2 = 0.f;
    #pragma unroll
    for (int q = 0; q < 4; ++q) { float ddv = v[q] - mu; p2 += ddv * ddv; }
    red[t] = p2;
    __syncthreads();
    for (int s = 128; s > 0; s >>= 1) { if (t < s) red[t] += red[t + s]; __syncthreads(); }
    float rs = rsqrtf(red[0] * (1.f / 1024.f) + EPS_);
    #pragma unroll
    for (int q = 0; q < 4; ++q) {
        int d = (db0 + q * 8) * 32 + dd;
        float zn = b2f(zb[(size_t)pos * 1024 + d]);
        float o = ((v[q] - mu) * rs * g[d] + bb[d]) * siluf_(zn);
        ycb[(size_t)pos * 1024 + d] = __float2bfloat16(o);
    }
}

// ---------------- implicit-GEMM 3x3 conv via bf16 MFMA, 8-way K-split over ci ----------------
__global__ __launch_bounds__(256) void k_conv2m(const __hip_bfloat16* __restrict__ vssb,
                                                const __hip_bfloat16* __restrict__ wt,
                                                float* __restrict__ convp) {
    __shared__ short Asm[18 * 18 * 32];
    __shared__ short Bsm[9 * 64 * 32];
    const int b = blockIdx.x, co0 = blockIdx.y * 64, split = blockIdx.z;  // split 0..7
    const int t = threadIdx.x;
    const int lane = t & 63, wid = t >> 6;
    const int wcol = lane & 15, slot = lane >> 4;

    f32x4 acc[4][4];
    #pragma unroll
    for (int r = 0; r < 4; ++r)
        #pragma unroll
        for (int g = 0; g < 4; ++g) acc[r][g] = (f32x4){0.f, 0.f, 0.f, 0.f};

    for (int ch = 0; ch < 2; ++ch) {
        const int ci0 = split * 64 + ch * 32;
        __syncthreads();
        for (int i = t; i < 324; i += 256) {
            int row = i / 18, col = i - row * 18;
            uint4 v0 = {0,0,0,0}, v1 = {0,0,0,0}, v2 = {0,0,0,0}, v3 = {0,0,0,0};
            if (row >= 1 && row <= 16 && col >= 1 && col <= 16) {
                const uint4* src = (const uint4*)(vssb + ((size_t)(b * 256 + (row - 1) * 16 + (col - 1)) * 512 + ci0));
                v0 = src[0]; v1 = src[1]; v2 = src[2]; v3 = src[3];
            }
            uint4* dst = (uint4*)(Asm + i * 32);
            int key = (col >> 1) & 3;
            dst[0 ^ key] = v0; dst[1 ^ key] = v1; dst[2 ^ key] = v2; dst[3 ^ key] = v3;
        }
        for (int i = t; i < 576; i += 256) {
            int tap = i >> 6, col = i & 63;
            const uint4* src = (const uint4*)(wt + ((size_t)(tap * 512 + co0 + col) * 512 + ci0));
            uint4* dst = (uint4*)(Bsm + i * 32);
            int key = (col >> 1) & 3;
            dst[0 ^ key] = src[0]; dst[1 ^ key] = src[1]; dst[2 ^ key] = src[2]; dst[3 ^ key] = src[3];
        }
        __syncthreads();
        #pragma unroll
        for (int tap = 0; tap < 9; ++tap) {
            const int ky = tap / 3, kx = tap - ky * 3;
            bf16x8 af[4], bfr[4];
            #pragma unroll
            for (int r = 0; r < 4; ++r) {
                int crow = wid * 4 + r + ky;
                int ccol = wcol + kx;
                int s2 = slot ^ ((ccol >> 1) & 3);
                af[r] = *(const bf16x8*)(Asm + ((crow * 18 + ccol) * 32 + s2 * 8));
            }
            #pragma unroll
            for (int g = 0; g < 4; ++g) {
                int col = g * 16 + wcol;
                int s2 = slot ^ ((col >> 1) & 3);
                bfr[g] = *(const bf16x8*)(Bsm + ((tap * 64 + col) * 32 + s2 * 8));
            }
            #pragma unroll
            for (int r = 0; r < 4; ++r)
                #pragma unroll
                for (int g = 0; g < 4; ++g)
                    acc[r][g] = __builtin_amdgcn_mfma_f32_16x16x32_bf16(af[r], bfr[g], acc[r][g], 0, 0, 0);
        }
    }
    float* base = convp + (size_t)split * 1048576 + (size_t)b * 512 * 256;
    #pragma unroll
    for (int r = 0; r < 4; ++r) {
        int h = wid * 4 + r;
        #pragma unroll
        for (int g = 0; g < 4; ++g) {
            int co = co0 + g * 16 + wcol;
            *(f32x4*)(base + (size_t)co * 256 + h * 16 + slot * 4) = acc[r][g];
        }
    }
}

// ---------------- reduce 8 K-splits + BN + relu6 -> t1b bf16 POS-MAJOR [b*256+pos][512] ----------------
__global__ __launch_bounds__(256) void k_convred2(const float* __restrict__ convp,
                                                  const float* __restrict__ bn_g, const float* __restrict__ bn_b,
                                                  const float* __restrict__ bn_mean, const float* __restrict__ bn_var,
                                                  __hip_bfloat16* __restrict__ t1b) {
    int b = blockIdx.x >> 7, cb = (blockIdx.x >> 3) & 15, pb = blockIdx.x & 7;
    int co0 = cb * 32, pos0 = pb * 32;
    int t = threadIdx.x;
    int ti = t >> 5, tj = t & 31;
    __shared__ float tile[32][33];
    #pragma unroll
    for (int r = 0; r < 4; ++r) {
        int co = co0 + ti + r * 8;
        size_t idx = ((size_t)b * 512 + co) * 256 + pos0 + tj;
        float s = 0.f;
        #pragma unroll
        for (int sp = 0; sp < 8; ++sp) s += convp[idx + (size_t)sp * 1048576];
        float o = (s - bn_mean[co]) * rsqrtf(bn_var[co] + EPS_) * bn_g[co] + bn_b[co];
        tile[ti + r * 8][tj] = fminf(fmaxf(o, 0.f), 6.f);
    }
    __syncthreads();
    #pragma unroll
    for (int r = 0; r < 4; ++r) {
        int pos = pos0 + ti + r * 8;
        t1b[((size_t)b * 256 + pos) * 512 + co0 + tj] = __float2bfloat16(tile[tj][ti + r * 8]);
    }
}

extern "C" void kernel_launch(void* const* d_in, const int* in_sizes, int n_in,
                              void* d_out, int out_size, void* d_ws, size_t ws_size,
                              hipStream_t stream) {
    const float* x = (const float*)d_in[0];
    const float* y = (const float*)d_in[1];
    const float* ln1_g = (const float*)d_in[2];
    const float* ln1_b = (const float*)d_in[3];
    const float* in_proj_w = (const float*)d_in[4];
    const float* conv_w = (const float*)d_in[5];
    const float* conv_b = (const float*)d_in[6];
    const float* x_proj_w = (const float*)d_in[7];
    const float* dt_w = (const float*)d_in[8];
    const float* dt_b = (const float*)d_in[9];
    const float* A_logs = (const float*)d_in[10];
    const float* Ds = (const float*)d_in[11];
    const float* out_norm_g = (const float*)d_in[12];
    const float* out_norm_b = (const float*)d_in[13];
    const float* out_proj_w = (const float*)d_in[14];
    const float* ffn_conv_w = (const float*)d_in[15];
    const float* bn_g = (const float*)d_in[16];
    const float* bn_b = (const float*)d_in[17];
    const float* bn_mean = (const float*)d_in[18];
    const float* bn_var = (const float*)d_in[19];
    const float* fc1_w = (const float*)d_in[20];
    const float* fc2_w = (const float*)d_in[21];
    const float* lin1_w = (const float*)d_in[22];
    const float* lin1_b = (const float*)d_in[23];
    const float* lin2_w = (const float*)d_in[24];
    const float* lin2_b = (const float*)d_in[25];
    float* out = (float*)d_out;

    char* ws = (char*)d_ws;
    size_t off = 0;
    auto alloc = [&](size_t nf) { float* p = (float*)(ws + off); off += nf * sizeof(float); return p; };
    float* xn    = alloc(2048u * 512);        // 4MB; xnb bf16 (2MB), then vssb bf16 (2MB)
    float* xa    = alloc(2048u * 1024);       // 8MB; xab bf16 (4MB), then ycb bf16 (4MB)
    float* z     = alloc(2048u * 1024);       // 8MB; zb bf16 (4MB)
    float* xs_t  = alloc(2u * 2048 * 1024);   // 16MB; xsb bf16 (8MB), then t1b (2MB) + t2b (2MB)
    float* x_dbl = alloc(8u * 4 * 256 * 64);  // 2MB f32
    float* ys_t  = alloc(4u * 2048 * 1024);   // 32MB; tiled delta/ys f32; then convp (32MB)
    float* wb    = alloc(2424832);            // 9.25MB bf16 weights (7 tensors)
    float* gate  = alloc(4096);

    __hip_bfloat16* xnb = (__hip_bfloat16*)xn;
    __hip_bfloat16* vssb = (__hip_bfloat16*)xn;         // after xnb dead
    __hip_bfloat16* xab = (__hip_bfloat16*)xa;
    __hip_bfloat16* ycb = (__hip_bfloat16*)xa;          // after xab dead (post-dwconv)
    __hip_bfloat16* zb  = (__hip_bfloat16*)z;
    __hip_bfloat16* xsb = (__hip_bfloat16*)xs_t;
    __hip_bfloat16* t1b = (__hip_bfloat16*)xs_t;        // after scan done
    __hip_bfloat16* t2b = (__hip_bfloat16*)(xs_t + 2048u * 512);
    float* convp = ys_t;
    __hip_bfloat16* inprojb = (__hip_bfloat16*)wb;
    __hip_bfloat16* xprojb  = inprojb + 1048576;
    __hip_bfloat16* outprojb = xprojb + 262144;
    __hip_bfloat16* fc1b = outprojb + 524288;
    __hip_bfloat16* fc2b = fc1b + 262144;
    __hip_bfloat16* dtwb = fc2b + 262144;
    __hip_bfloat16* w_t  = dtwb + 131072;               // ffn conv weights

    k_prologue<<<5512, 256, 0, stream>>>(in_proj_w, x_proj_w, out_proj_w, fc1_w, fc2_w, dt_w, ffn_conv_w,
                                         inprojb, x, ln1_g, ln1_b, xnb, y, lin1_w, lin1_b, lin2_w, lin2_b, gate);
    gemm_mfma<M_INPROJ><<<dim3(32, 32), 256, 0, stream>>>(xnb, inprojb, nullptr, (float*)zb, nullptr, xab);
    k_dwconv2<<<2048, 256, 0, stream>>>(xab, conv_w, conv_b, xsb);
    gemm_mfma<M_XDBL><<<dim3(32, 4), 256, 0, stream>>>(xsb, xprojb, x_dbl, nullptr, nullptr, nullptr);
    gemm_mfma<M_DELTA><<<dim3(128, 16), 256, 0, stream>>>(x_dbl, dtwb, ys_t, nullptr, dt_b, nullptr);
    k_scan7<<<1024, 512, 0, stream>>>(xsb, x_dbl, A_logs, Ds, ys_t);
    k_combine<<<2048, 256, 0, stream>>>(ys_t, zb, out_norm_g, out_norm_b, ycb);
    gemm_mfma<M_OUTPROJ><<<dim3(32, 8), 256, 0, stream>>>(ycb, outprojb, nullptr, nullptr, x, vssb);
    k_conv2m<<<dim3(8, 8, 8), 256, 0, stream>>>(vssb, w_t, convp);
    k_convred2<<<1024, 256, 0, stream>>>(convp, bn_g, bn_b, bn_mean, bn_var, t1b);
    gemm_mfma<M_FC1><<<dim3(32, 8), 256, 0, stream>>>(t1b, fc1b, nullptr, nullptr, nullptr, t2b);
    gemm_mfma<M_FC2><<<dim3(64, 4), 256, 0, stream>>>(t2b, fc2b, out, nullptr, gate, nullptr);
}